// Round 8
// baseline (792.776 us; speedup 1.0000x reference)
//
#include <hip/hip_runtime.h>

constexpr int H    = 128;
constexpr int NN   = 10000;
constexpr int EE   = 160000;
constexpr int RCN  = 4;      // R*C
constexpr int NG   = 64;     // graphs per replica
constexpr int OUTF = 64;
constexpr int DSEG = 256;    // RCN*NG

using short8 = __attribute__((ext_vector_type(8))) short;
using f32x4  = __attribute__((ext_vector_type(4))) float;

// Exact-GELU via A&S 7.1.26 erf (|err|<=1.5e-7 abs)
__device__ __forceinline__ float gelu_f(float x){
  float z  = x*0.70710678118654752440f;
  float az = fabsf(z);
  float t  = __builtin_amdgcn_rcpf(fmaf(az, 0.3275911f, 1.0f));
  float e  = __expf(-z*z);
  float poly = fmaf(fmaf(fmaf(fmaf(1.061405429f, t, -1.453152027f),
                              t, 1.421413741f),
                         t, -0.284496736f),
                    t, 0.254829592f) * t;
  float er = fmaf(-poly, e, 1.0f);
  er = copysignf(er, z);
  return 0.5f*x*(1.0f + er);
}

__device__ __forceinline__ void split3(float x, unsigned short& h,
                                       unsigned short& m, unsigned short& l){
  unsigned int u = __float_as_uint(x);
  unsigned int rh = u + 0x7FFF + ((u>>16)&1);
  h = (unsigned short)(rh>>16);
  float fh = __uint_as_float((unsigned int)h << 16);
  float r1 = x - fh;
  unsigned int u1 = __float_as_uint(r1);
  unsigned int rm = u1 + 0x7FFF + ((u1>>16)&1);
  m = (unsigned short)(rm>>16);
  float fm = __uint_as_float((unsigned int)m << 16);
  float r2 = r1 - fm;
  unsigned int u2 = __float_as_uint(r2);
  unsigned int rl = u2 + 0x7FFF + ((u2>>16)&1);
  l = (unsigned short)(rl>>16);
}

// ---------- edge mask
__global__ void k_edge_mask(const int* __restrict__ src, const int* __restrict__ dst,
                            const float* __restrict__ nm, float4* __restrict__ em4){
  int e = blockIdx.x*256 + threadIdx.x;
  if(e >= EE) return;
  int s = src[e], d = dst[e];
  float4 m;
  m.x = nm[0*NN+s]*nm[0*NN+d];
  m.y = nm[1*NN+s]*nm[1*NN+d];
  m.z = nm[2*NN+s]*nm[2*NN+d];
  m.w = nm[3*NN+s]*nm[3*NN+d];
  em4[e] = m;
}

// ---------- CSR build
__global__ void k_hist(const int* __restrict__ dst, int* __restrict__ cnt){
  int e = blockIdx.x*256 + threadIdx.x;
  if(e < EE) atomicAdd(&cnt[dst[e]], 1);
}

__global__ __launch_bounds__(1024) void k_scan(const int* __restrict__ cnt,
                                               int* __restrict__ rs, int* __restrict__ cur){
  __shared__ int part[1024];
  int t = threadIdx.x;
  const int CH = 10;
  int base = t*CH;
  int s = 0;
  #pragma unroll
  for(int j=0;j<CH;j++){ int i = base+j; if(i<NN) s += cnt[i]; }
  part[t] = s;
  __syncthreads();
  for(int off=1; off<1024; off<<=1){
    int v = (t>=off) ? part[t-off] : 0;
    __syncthreads();
    part[t] += v;
    __syncthreads();
  }
  int run = (t==0) ? 0 : part[t-1];
  #pragma unroll
  for(int j=0;j<CH;j++){
    int i = base+j;
    if(i<NN){ rs[i] = run; cur[i] = run; run += cnt[i]; }
  }
  if(t == 1023) rs[NN] = part[1023];
}

__global__ void k_fill(const int* __restrict__ dst,
                       int* __restrict__ cur, int* __restrict__ eid){
  int e = blockIdx.x*256 + threadIdx.x;
  if(e >= EE) return;
  int p = atomicAdd(&cur[dst[e]], 1);
  eid[p] = e;
}

__global__ void k_sortcsr(const int* __restrict__ rs, int* __restrict__ eid,
                          const int* __restrict__ src, int* __restrict__ esrc){
  int n = blockIdx.x*256 + threadIdx.x;
  if(n >= NN) return;
  int jb = rs[n], je = rs[n+1];
  for(int j=jb+1; j<je; j++){
    int v = eid[j];
    int k = j-1;
    while(k >= jb && eid[k] > v){ eid[k+1] = eid[k]; k--; }
    eid[k+1] = v;
  }
  for(int j=jb; j<je; j++) esrc[j] = src[eid[j]];
}

__global__ void k_gbounds(const int* __restrict__ batch, int* __restrict__ gs){
  int g = threadIdx.x;
  if(g > NG) return;
  if(g == NG){ gs[NG] = NN; return; }
  int lo = 0, hi = NN;
  while(lo < hi){
    int mid = (lo+hi)>>1;
    if(batch[mid] < g) lo = mid+1; else hi = mid;
  }
  gs[g] = lo;
}

// ---------- split W (fp32 -> 3x bf16) into MFMA B-fragment-linear layout
__global__ void k_splitW(const float* __restrict__ W, unsigned short* __restrict__ oh,
                         unsigned short* __restrict__ om, unsigned short* __restrict__ ol,
                         int nmat, int N){
  int tid = blockIdx.x*256 + threadIdx.x;
  int total = nmat*128*N;
  if(tid >= total) return;
  int mat = tid / (128*N);
  int rem = tid - mat*(128*N);
  int k = rem / N;
  int n = rem - k*N;
  int NF = N >> 4;
  int ks = k >> 5, kk = k & 31;
  int nf = n >> 4;
  int lane = (n & 15) + 16*((kk & 15) >> 2);
  int e = 4*(kk >> 4) + (kk & 3);
  size_t idx = (size_t)mat*128*N + ((size_t)(ks*NF + nf)*64 + lane)*8 + e;
  unsigned short hh, mm, ll;
  split3(W[tid], hh, mm, ll);
  oh[idx] = hh; om[idx] = mm; ol[idx] = ll;
}

// ---------- split A (edge_attr, fp32 -> 3x bf16) into MFMA A-fragment-linear layout
// one thread per k-quad: row = tid>>5, k = (tid&31)*4
__global__ void k_splitA(const float* __restrict__ A, unsigned short* __restrict__ oh,
                         unsigned short* __restrict__ om, unsigned short* __restrict__ ol){
  int tid = blockIdx.x*256 + threadIdx.x;
  if(tid >= EE*32) return;
  int row = tid >> 5, kq = tid & 31;
  int k = kq*4;
  float4 v = *(const float4*)&A[(size_t)row*H + k];
  int ks = k >> 5, kk = k & 31;
  int kg = (kk & 15) >> 2;
  int eb = 4*(kk >> 4);
  int lane = (row & 15) + 16*kg;
  size_t idx = (((size_t)(row >> 4)*4 + ks)*64 + lane)*8 + eb;
  ushort4 hh, mm, ll;
  split3(v.x, hh.x, mm.x, ll.x);
  split3(v.y, hh.y, mm.y, ll.y);
  split3(v.z, hh.z, mm.z, ll.z);
  split3(v.w, hh.w, mm.w, ll.w);
  *(ushort4*)&oh[idx] = hh;
  *(ushort4*)&om[idx] = mm;
  *(ushort4*)&ol[idx] = ll;
}

// ---------- emb GEMM from pre-split frag-linear A and W: no LDS, no barriers
__global__ __launch_bounds__(256, 3) void k_egemm(
    const unsigned short* __restrict__ Ah, const unsigned short* __restrict__ Am,
    const unsigned short* __restrict__ Alo,
    const unsigned short* __restrict__ Wh, const unsigned short* __restrict__ Wm,
    const unsigned short* __restrict__ Wl, const float* __restrict__ bias,
    float* __restrict__ C){
  constexpr int NF = 8;
  int t = threadIdx.x;
  int w = t >> 6, lane = t & 63;
  int m15 = lane & 15, kg = lane >> 4;
  int rowbase = blockIdx.x*128;
  int rtb = blockIdx.x*8 + w*2;       // row-tile base for this wave (2 tiles of 16 rows)

  const int SMAX = 4*NF - 1;
  auto ldW = [&](int s, short8* d){
    size_t widx = ((size_t)s*64 + lane)*8;
    d[0] = *(const short8*)&Wh[widx];
    d[1] = *(const short8*)&Wm[widx];
    d[2] = *(const short8*)&Wl[widx];
  };

  f32x4 acc[2][NF];
  #pragma unroll
  for(int mf=0;mf<2;mf++)
    #pragma unroll
    for(int nf=0;nf<NF;nf++) acc[mf][nf] = (f32x4){0.f,0.f,0.f,0.f};

  short8 cw[3], nw[3];
  ldW(0, cw);
  ldW(1, nw);

  for(int ks=0;ks<4;ks++){
    short8 ah[2], am[2], alo[2];
    #pragma unroll
    for(int mf=0;mf<2;mf++){
      size_t aidx = (((size_t)(rtb+mf)*4 + ks)*64 + lane)*8;
      ah[mf]  = *(const short8*)&Ah[aidx];
      am[mf]  = *(const short8*)&Am[aidx];
      alo[mf] = *(const short8*)&Alo[aidx];
    }
    #pragma unroll
    for(int nf=0;nf<NF;nf++){
      int s = ks*NF + nf;
      short8 pw[3];
      ldW(s+2 <= SMAX ? s+2 : SMAX, pw);
      #pragma unroll
      for(int mf=0;mf<2;mf++){
        acc[mf][nf] = __builtin_amdgcn_mfma_f32_16x16x32_bf16(ah[mf],  cw[0], acc[mf][nf], 0,0,0);
        acc[mf][nf] = __builtin_amdgcn_mfma_f32_16x16x32_bf16(ah[mf],  cw[1], acc[mf][nf], 0,0,0);
        acc[mf][nf] = __builtin_amdgcn_mfma_f32_16x16x32_bf16(am[mf],  cw[0], acc[mf][nf], 0,0,0);
        acc[mf][nf] = __builtin_amdgcn_mfma_f32_16x16x32_bf16(ah[mf],  cw[2], acc[mf][nf], 0,0,0);
        acc[mf][nf] = __builtin_amdgcn_mfma_f32_16x16x32_bf16(alo[mf], cw[0], acc[mf][nf], 0,0,0);
        acc[mf][nf] = __builtin_amdgcn_mfma_f32_16x16x32_bf16(am[mf],  cw[1], acc[mf][nf], 0,0,0);
      }
      cw[0]=nw[0]; cw[1]=nw[1]; cw[2]=nw[2];
      nw[0]=pw[0]; nw[1]=pw[1]; nw[2]=pw[2];
    }
  }
  #pragma unroll
  for(int mf=0;mf<2;mf++){
    #pragma unroll
    for(int nf=0;nf<NF;nf++){
      int gcol = nf*16 + m15;
      float bv = bias[gcol];
      #pragma unroll
      for(int r=0;r<4;r++){
        int grow = rowbase + w*32 + mf*16 + kg*4 + r;
        C[(size_t)grow*H + gcol] = acc[mf][nf][r] + bv;
      }
    }
  }
}

// ---------- MFMA GEMM (node side): A fp32 staged in LDS, split in-reg, bf16x3
template<int NF, bool GELU>
__global__ __launch_bounds__(256) void k_mgemm(const float* __restrict__ A,
    const unsigned short* __restrict__ Wh, const unsigned short* __restrict__ Wm,
    const unsigned short* __restrict__ Wl, const float* __restrict__ bias,
    float* __restrict__ C, int nrows){
  __shared__ float Al[128*132];
  int t = threadIdx.x;
  int rowbase = blockIdx.x*128;
  #pragma unroll
  for(int i=0;i<16;i++){
    int idx = i*256 + t;
    int r = idx >> 5, c4 = idx & 31;
    int gr = rowbase + r;
    float4 v = {0.f,0.f,0.f,0.f};
    if(gr < nrows) v = *(const float4*)&A[(size_t)gr*H + c4*4];
    *(float4*)&Al[r*132 + c4*4] = v;
  }
  __syncthreads();
  int w = t >> 6, lane = t & 63;
  int m15 = lane & 15, kg = lane >> 4;

  const int SMAX = 4*NF - 1;
  auto ldW = [&](int s, short8* d){
    size_t widx = ((size_t)s*64 + lane)*8;
    d[0] = *(const short8*)&Wh[widx];
    d[1] = *(const short8*)&Wm[widx];
    d[2] = *(const short8*)&Wl[widx];
  };

  f32x4 acc[2][NF];
  #pragma unroll
  for(int mf=0;mf<2;mf++)
    #pragma unroll
    for(int nf=0;nf<NF;nf++) acc[mf][nf] = (f32x4){0.f,0.f,0.f,0.f};

  short8 cw[3], nw[3];
  ldW(0, cw);
  ldW(1 <= SMAX ? 1 : SMAX, nw);

  for(int ks=0;ks<4;ks++){
    short8 ah[2], am[2], alo[2];
    #pragma unroll
    for(int mf=0;mf<2;mf++){
      int row = w*32 + mf*16 + m15;
      const float* base = &Al[row*132 + ks*32 + kg*4];
      float4 f0 = *(const float4*)base;
      float4 f1 = *(const float4*)(base + 16);
      float vs[8] = {f0.x,f0.y,f0.z,f0.w,f1.x,f1.y,f1.z,f1.w};
      #pragma unroll
      for(int e=0;e<8;e++){
        unsigned short hh, mv, lv;
        split3(vs[e], hh, mv, lv);
        ah[mf][e]  = (short)hh;
        am[mf][e]  = (short)mv;
        alo[mf][e] = (short)lv;
      }
    }
    #pragma unroll
    for(int nf=0;nf<NF;nf++){
      int s = ks*NF + nf;
      short8 pw[3];
      ldW(s+2 <= SMAX ? s+2 : SMAX, pw);
      #pragma unroll
      for(int mf=0;mf<2;mf++){
        acc[mf][nf] = __builtin_amdgcn_mfma_f32_16x16x32_bf16(ah[mf],  cw[0], acc[mf][nf], 0,0,0);
        acc[mf][nf] = __builtin_amdgcn_mfma_f32_16x16x32_bf16(ah[mf],  cw[1], acc[mf][nf], 0,0,0);
        acc[mf][nf] = __builtin_amdgcn_mfma_f32_16x16x32_bf16(am[mf],  cw[0], acc[mf][nf], 0,0,0);
        acc[mf][nf] = __builtin_amdgcn_mfma_f32_16x16x32_bf16(ah[mf],  cw[2], acc[mf][nf], 0,0,0);
        acc[mf][nf] = __builtin_amdgcn_mfma_f32_16x16x32_bf16(alo[mf], cw[0], acc[mf][nf], 0,0,0);
        acc[mf][nf] = __builtin_amdgcn_mfma_f32_16x16x32_bf16(am[mf],  cw[1], acc[mf][nf], 0,0,0);
      }
      cw[0]=nw[0]; cw[1]=nw[1]; cw[2]=nw[2];
      nw[0]=pw[0]; nw[1]=pw[1]; nw[2]=pw[2];
    }
  }
  const int N = NF*16;
  #pragma unroll
  for(int mf=0;mf<2;mf++){
    #pragma unroll
    for(int nf=0;nf<NF;nf++){
      int gcol = nf*16 + m15;
      float bv = bias[gcol];
      #pragma unroll
      for(int r=0;r<4;r++){
        int grow = rowbase + w*32 + mf*16 + kg*4 + r;
        if(grow < nrows){
          float v = acc[mf][nf][r] + bv;
          if(GELU) v = gelu_f(v);
          C[(size_t)grow*N + gcol] = v;
        }
      }
    }
  }
}

// ---------- aggregation: one wave per node, rc-pair per half-wave, 1-deep prefetch
template<bool FIRST>
__global__ __launch_bounds__(256) void k_agg(const float* __restrict__ hin, const float* __restrict__ emb,
                       const float4* __restrict__ em4, const int* __restrict__ rs,
                       const int* __restrict__ eid, const int* __restrict__ esrc,
                       const float* __restrict__ epsp, float* __restrict__ tout){
  int t = threadIdx.x;
  int w = t >> 6;
  int lane = t & 63;
  int half = lane >> 5;
  int l32 = lane & 31;
  int n = blockIdx.x*4 + w;
  int d0 = l32*4;
  int rc0 = half*2, rc1 = rc0+1;
  float4 acc0 = {0.f,0.f,0.f,0.f}, acc1 = {0.f,0.f,0.f,0.f};
  int jb = rs[n], je = rs[n+1];
  if(jb < je){
    int e = eid[jb], s = esrc[jb];
    float4 ev = *(const float4*)&emb[(size_t)e*H + d0];
    float4 m  = em4[e];
    float4 h0, h1;
    if(FIRST){
      h0 = *(const float4*)&hin[(size_t)s*H + d0];
      h1 = h0;
    } else {
      h0 = *(const float4*)&hin[((size_t)rc0*NN + s)*H + d0];
      h1 = *(const float4*)&hin[((size_t)rc1*NN + s)*H + d0];
    }
    for(int j=jb; j<je; j++){
      float4 ev_n = {0,0,0,0}, m_n = {0,0,0,0}, h0_n = {0,0,0,0}, h1_n = {0,0,0,0};
      if(j+1 < je){
        int e2 = eid[j+1], s2 = esrc[j+1];
        ev_n = *(const float4*)&emb[(size_t)e2*H + d0];
        m_n  = em4[e2];
        if(FIRST){
          h0_n = *(const float4*)&hin[(size_t)s2*H + d0];
          h1_n = h0_n;
        } else {
          h0_n = *(const float4*)&hin[((size_t)rc0*NN + s2)*H + d0];
          h1_n = *(const float4*)&hin[((size_t)rc1*NN + s2)*H + d0];
        }
      }
      float m0 = half ? m.z : m.x;
      float m1 = half ? m.w : m.y;
      if(FIRST){
        float gx = gelu_f(h0.x+ev.x);
        float gy = gelu_f(h0.y+ev.y);
        float gz = gelu_f(h0.z+ev.z);
        float gw = gelu_f(h0.w+ev.w);
        acc0.x += gx*m0; acc0.y += gy*m0; acc0.z += gz*m0; acc0.w += gw*m0;
        acc1.x += gx*m1; acc1.y += gy*m1; acc1.z += gz*m1; acc1.w += gw*m1;
      } else {
        acc0.x += gelu_f(h0.x+ev.x)*m0;
        acc0.y += gelu_f(h0.y+ev.y)*m0;
        acc0.z += gelu_f(h0.z+ev.z)*m0;
        acc0.w += gelu_f(h0.w+ev.w)*m0;
        acc1.x += gelu_f(h1.x+ev.x)*m1;
        acc1.y += gelu_f(h1.y+ev.y)*m1;
        acc1.z += gelu_f(h1.z+ev.z)*m1;
        acc1.w += gelu_f(h1.w+ev.w)*m1;
      }
      ev = ev_n; m = m_n; h0 = h0_n; h1 = h1_n;
    }
  }
  float e1 = 1.0f + epsp[0];
  {
    const float* hb = FIRST ? (hin + (size_t)n*H) : (hin + ((size_t)rc0*NN + n)*H);
    float4 hv = *(const float4*)&hb[d0];
    float4 o;
    o.x = e1*hv.x + acc0.x; o.y = e1*hv.y + acc0.y;
    o.z = e1*hv.z + acc0.z; o.w = e1*hv.w + acc0.w;
    *(float4*)&tout[((size_t)rc0*NN + n)*H + d0] = o;
  }
  {
    const float* hb = FIRST ? (hin + (size_t)n*H) : (hin + ((size_t)rc1*NN + n)*H);
    float4 hv = *(const float4*)&hb[d0];
    float4 o;
    o.x = e1*hv.x + acc1.x; o.y = e1*hv.y + acc1.y;
    o.z = e1*hv.z + acc1.z; o.w = e1*hv.w + acc1.w;
    *(float4*)&tout[((size_t)rc1*NN + n)*H + d0] = o;
  }
}

// ---------- deterministic masked segment mean
__global__ __launch_bounds__(64) void k_pool(const float* __restrict__ y, const float* __restrict__ nm,
                       const int* __restrict__ gs, float* __restrict__ out){
  int seg = blockIdx.x;
  int rc = seg / NG;
  int g  = seg - rc*NG;
  int c  = threadIdx.x;
  int nb = gs[g], ne = gs[g+1];
  float num = 0.f, den = 0.f;
  for(int n=nb; n<ne; n++){
    float w = nm[rc*NN + n];
    num += y[((size_t)rc*NN + n)*OUTF + c] * w;
    den += w;
  }
  out[seg*OUTF + c] = num / fmaxf(den, 1e-12f);
}

extern "C" void kernel_launch(void* const* d_in, const int* in_sizes, int n_in,
                              void* d_out, int out_size, void* d_ws, size_t ws_size,
                              hipStream_t stream){
  const float* x         = (const float*)d_in[0];
  const float* edge_attr = (const float*)d_in[1];
  const float* node_mask = (const float*)d_in[2];
  const float* bond_W    = (const float*)d_in[3];
  const float* bond_b    = (const float*)d_in[4];
  const float* epsv      = (const float*)d_in[5];
  const float* conv_W1   = (const float*)d_in[6];
  const float* conv_b1   = (const float*)d_in[7];
  const float* conv_W2   = (const float*)d_in[8];
  const float* conv_b2   = (const float*)d_in[9];
  const float* mlp_W1    = (const float*)d_in[10];
  const float* mlp_b1    = (const float*)d_in[11];
  const float* mlp_W2    = (const float*)d_in[12];
  const float* mlp_b2    = (const float*)d_in[13];
  const int*   eidx      = (const int*)d_in[14];
  const int*   batch     = (const int*)d_in[15];
  const int* srcp = eidx;
  const int* dstp = eidx + EE;

  char* p = (char*)d_ws;
  auto alloc = [&](size_t bytes)->char*{
    char* r = p; p += (bytes + 255) & ~size_t(255); return r;
  };
  float*  h    = (float*) alloc((size_t)RCN*NN*H*4);
  float*  tbuf = (float*) alloc((size_t)RCN*NN*H*4);
  float*  u    = (float*) alloc((size_t)RCN*NN*H*4);
  float*  emb  = (float*) alloc((size_t)EE*H*4);
  float4* em4  = (float4*)alloc((size_t)EE*16);
  float*  y    = (float*) alloc((size_t)RCN*NN*OUTF*4);
  int*    cnt  = (int*)   alloc((size_t)NN*4);
  int*    rs   = (int*)   alloc((size_t)(NN+1)*4);
  int*    cur  = (int*)   alloc((size_t)NN*4);
  int*    eid  = (int*)   alloc((size_t)EE*4);
  int*    esrc = (int*)   alloc((size_t)EE*4);
  int*    gs   = (int*)   alloc((size_t)(NG+1)*4);
  // split-W buffers
  unsigned short* WBh  = (unsigned short*)alloc((size_t)3*16384*2);
  unsigned short* WBm  = (unsigned short*)alloc((size_t)3*16384*2);
  unsigned short* WBl  = (unsigned short*)alloc((size_t)3*16384*2);
  unsigned short* WC1h = (unsigned short*)alloc((size_t)3*16384*2);
  unsigned short* WC1m = (unsigned short*)alloc((size_t)3*16384*2);
  unsigned short* WC1l = (unsigned short*)alloc((size_t)3*16384*2);
  unsigned short* WC2h = (unsigned short*)alloc((size_t)3*16384*2);
  unsigned short* WC2m = (unsigned short*)alloc((size_t)3*16384*2);
  unsigned short* WC2l = (unsigned short*)alloc((size_t)3*16384*2);
  unsigned short* WM1h = (unsigned short*)alloc((size_t)16384*2);
  unsigned short* WM1m = (unsigned short*)alloc((size_t)16384*2);
  unsigned short* WM1l = (unsigned short*)alloc((size_t)16384*2);
  unsigned short* WM2h = (unsigned short*)alloc((size_t)8192*2);
  unsigned short* WM2m = (unsigned short*)alloc((size_t)8192*2);
  unsigned short* WM2l = (unsigned short*)alloc((size_t)8192*2);
  // pre-split edge_attr (frag-linear bf16 planes)
  unsigned short* EAh  = (unsigned short*)alloc((size_t)EE*H*2);
  unsigned short* EAm  = (unsigned short*)alloc((size_t)EE*H*2);
  unsigned short* EAl  = (unsigned short*)alloc((size_t)EE*H*2);
  if((size_t)(p - (char*)d_ws) > ws_size) return;

  hipMemsetAsync(cnt, 0, (size_t)NN*4, stream);

  k_edge_mask<<<(EE+255)/256, 256, 0, stream>>>(srcp, dstp, node_mask, em4);
  k_hist     <<<(EE+255)/256, 256, 0, stream>>>(dstp, cnt);
  k_scan     <<<1, 1024, 0, stream>>>(cnt, rs, cur);
  k_fill     <<<(EE+255)/256, 256, 0, stream>>>(dstp, cur, eid);
  k_sortcsr  <<<(NN+255)/256, 256, 0, stream>>>(rs, eid, srcp, esrc);
  k_gbounds  <<<1, 128, 0, stream>>>(batch, gs);
  k_splitW   <<<192, 256, 0, stream>>>(bond_W,  WBh,  WBm,  WBl,  3, 128);
  k_splitW   <<<192, 256, 0, stream>>>(conv_W1, WC1h, WC1m, WC1l, 3, 128);
  k_splitW   <<<192, 256, 0, stream>>>(conv_W2, WC2h, WC2m, WC2l, 3, 128);
  k_splitW   <<<64,  256, 0, stream>>>(mlp_W1,  WM1h, WM1m, WM1l, 1, 128);
  k_splitW   <<<32,  256, 0, stream>>>(mlp_W2,  WM2h, WM2m, WM2l, 1, 64);
  k_splitA   <<<EE*32/256, 256, 0, stream>>>(edge_attr, EAh, EAm, EAl);

  const int NROWS = RCN*NN;
  const int GB_E = EE/128;             // 1250
  const int GB_N = (NROWS+127)/128;    // 313
  for(int l=0; l<3; l++){
    size_t wo = (size_t)l*16384;
    k_egemm<<<GB_E, 256, 0, stream>>>(EAh, EAm, EAl, WBh+wo, WBm+wo, WBl+wo,
                                      bond_b + l*H, emb);
    if(l == 0)
      k_agg<true ><<<NN/4, 256, 0, stream>>>(x, emb, em4, rs, eid, esrc, epsv + l, tbuf);
    else
      k_agg<false><<<NN/4, 256, 0, stream>>>(h, emb, em4, rs, eid, esrc, epsv + l, tbuf);
    k_mgemm<8,true><<<GB_N, 256, 0, stream>>>(tbuf, WC1h+wo, WC1m+wo, WC1l+wo,
                                              conv_b1 + l*H, u, NROWS);
    k_mgemm<8,true><<<GB_N, 256, 0, stream>>>(u, WC2h+wo, WC2m+wo, WC2l+wo,
                                              conv_b2 + l*H, h, NROWS);
  }
  k_mgemm<8,true><<<GB_N, 256, 0, stream>>>(h, WM1h, WM1m, WM1l, mlp_b1, u, NROWS);
  k_mgemm<4,false><<<GB_N, 256, 0, stream>>>(u, WM2h, WM2m, WM2l, mlp_b2, y, NROWS);
  k_pool<<<DSEG, 64, 0, stream>>>(y, node_mask, gs, (float*)d_out);
}

// Round 10
// 762.421 us; speedup vs baseline: 1.0398x; 1.0398x over previous
//
#include <hip/hip_runtime.h>

constexpr int H    = 128;
constexpr int NN   = 10000;
constexpr int EE   = 160000;
constexpr int RCN  = 4;      // R*C
constexpr int NG   = 64;     // graphs per replica
constexpr int OUTF = 64;
constexpr int DSEG = 256;    // RCN*NG

using short8 = __attribute__((ext_vector_type(8))) short;
using f32x4  = __attribute__((ext_vector_type(4))) float;

// Exact-GELU via A&S 7.1.26 erf (|err|<=1.5e-7 abs)
__device__ __forceinline__ float gelu_f(float x){
  float z  = x*0.70710678118654752440f;
  float az = fabsf(z);
  float t  = __builtin_amdgcn_rcpf(fmaf(az, 0.3275911f, 1.0f));
  float e  = __expf(-z*z);
  float poly = fmaf(fmaf(fmaf(fmaf(1.061405429f, t, -1.453152027f),
                              t, 1.421413741f),
                         t, -0.284496736f),
                    t, 0.254829592f) * t;
  float er = fmaf(-poly, e, 1.0f);
  er = copysignf(er, z);
  return 0.5f*x*(1.0f + er);
}

// RNE 2-way split: x ~= h + m with |residual| <= ~2^-17 |x|
__device__ __forceinline__ void split2(float x, unsigned short& h, unsigned short& m){
  unsigned int u = __float_as_uint(x);
  unsigned int rh = u + 0x7FFF + ((u>>16)&1);
  h = (unsigned short)(rh>>16);
  float fh = __uint_as_float((unsigned int)h << 16);
  float r1 = x - fh;
  unsigned int u1 = __float_as_uint(r1);
  unsigned int rm = u1 + 0x7FFF + ((u1>>16)&1);
  m = (unsigned short)(rm>>16);
}

// ---------- CSR build
__global__ void k_hist(const int* __restrict__ dst, int* __restrict__ cnt){
  int e = blockIdx.x*256 + threadIdx.x;
  if(e < EE) atomicAdd(&cnt[dst[e]], 1);
}

__global__ __launch_bounds__(1024) void k_scan(const int* __restrict__ cnt,
                                               int* __restrict__ rs, int* __restrict__ cur){
  __shared__ int part[1024];
  int t = threadIdx.x;
  const int CH = 10;
  int base = t*CH;
  int s = 0;
  #pragma unroll
  for(int j=0;j<CH;j++){ int i = base+j; if(i<NN) s += cnt[i]; }
  part[t] = s;
  __syncthreads();
  for(int off=1; off<1024; off<<=1){
    int v = (t>=off) ? part[t-off] : 0;
    __syncthreads();
    part[t] += v;
    __syncthreads();
  }
  int run = (t==0) ? 0 : part[t-1];
  #pragma unroll
  for(int j=0;j<CH;j++){
    int i = base+j;
    if(i<NN){ rs[i] = run; cur[i] = run; run += cnt[i]; }
  }
  if(t == 1023) rs[NN] = part[1023];
}

__global__ void k_fill(const int* __restrict__ dst,
                       int* __restrict__ cur, int* __restrict__ eid){
  int e = blockIdx.x*256 + threadIdx.x;
  if(e >= EE) return;
  int p = atomicAdd(&cur[dst[e]], 1);
  eid[p] = e;
}

__global__ void k_sortcsr(const int* __restrict__ rs, int* __restrict__ eid,
                          const int* __restrict__ src, int* __restrict__ esrc){
  int n = blockIdx.x*256 + threadIdx.x;
  if(n >= NN) return;
  int jb = rs[n], je = rs[n+1];
  for(int j=jb+1; j<je; j++){
    int v = eid[j];
    int k = j-1;
    while(k >= jb && eid[k] > v){ eid[k+1] = eid[k]; k--; }
    eid[k+1] = v;
  }
  for(int j=jb; j<je; j++) esrc[j] = src[eid[j]];
}

__global__ void k_gbounds(const int* __restrict__ batch, int* __restrict__ gs){
  int g = threadIdx.x;
  if(g > NG) return;
  if(g == NG){ gs[NG] = NN; return; }
  int lo = 0, hi = NN;
  while(lo < hi){
    int mid = (lo+hi)>>1;
    if(batch[mid] < g) lo = mid+1; else hi = mid;
  }
  gs[g] = lo;
}

// ---------- edge mask in CSR-permuted order
__global__ void k_emaskp(const int* __restrict__ src, const int* __restrict__ dst,
                         const int* __restrict__ eid, const float* __restrict__ nm,
                         float4* __restrict__ em4p){
  int j = blockIdx.x*256 + threadIdx.x;
  if(j >= EE) return;
  int e = eid[j];
  int s = src[e], d = dst[e];
  float4 m;
  m.x = nm[0*NN+s]*nm[0*NN+d];
  m.y = nm[1*NN+s]*nm[1*NN+d];
  m.z = nm[2*NN+s]*nm[2*NN+d];
  m.w = nm[3*NN+s]*nm[3*NN+d];
  em4p[j] = m;
}

// ---------- split W (fp32 -> 2x bf16) into MFMA B-fragment-linear layout
__global__ void k_splitW(const float* __restrict__ W, unsigned short* __restrict__ oh,
                         unsigned short* __restrict__ om, int nmat, int N){
  int tid = blockIdx.x*256 + threadIdx.x;
  int total = nmat*128*N;
  if(tid >= total) return;
  int mat = tid / (128*N);
  int rem = tid - mat*(128*N);
  int k = rem / N;
  int n = rem - k*N;
  int NF = N >> 4;
  int ks = k >> 5, kk = k & 31;
  int nf = n >> 4;
  int lane = (n & 15) + 16*((kk & 15) >> 2);
  int e = 4*(kk >> 4) + (kk & 3);
  size_t idx = (size_t)mat*128*N + ((size_t)(ks*NF + nf)*64 + lane)*8 + e;
  unsigned short hh, mm;
  split2(W[tid], hh, mm);
  oh[idx] = hh; om[idx] = mm;
}

// ---------- split edge_attr into CSR-PERMUTED A-fragment-linear planes (bf16x2)
__global__ void k_splitA(const float* __restrict__ A, const int* __restrict__ eid,
                         unsigned short* __restrict__ oh, unsigned short* __restrict__ om){
  int tid = blockIdx.x*256 + threadIdx.x;
  if(tid >= EE*32) return;
  int j = tid >> 5, kq = tid & 31;
  int k = kq*4;
  int rsrc = eid[j];
  float4 v = *(const float4*)&A[(size_t)rsrc*H + k];
  int ks = k >> 5, kk = k & 31;
  int kg = (kk & 15) >> 2;
  int eb = 4*(kk >> 4);
  int lane = (j & 15) + 16*kg;
  size_t idx = (((size_t)(j >> 4)*4 + ks)*64 + lane)*8 + eb;
  ushort4 hh, mm;
  split2(v.x, hh.x, mm.x);
  split2(v.y, hh.y, mm.y);
  split2(v.z, hh.z, mm.z);
  split2(v.w, hh.w, mm.w);
  *(ushort4*)&oh[idx] = hh;
  *(ushort4*)&om[idx] = mm;
}

// ---------- unified split-input MFMA GEMM (bf16x2, 3 terms), no LDS, no barriers
template<int NFO, bool GELU, bool OUTP, bool OUTF32>
__global__ __launch_bounds__(256) void k_sgemm(
    const unsigned short* __restrict__ Ah, const unsigned short* __restrict__ Am,
    const unsigned short* __restrict__ Wh, const unsigned short* __restrict__ Wm,
    const float* __restrict__ bias, float* __restrict__ Cf,
    unsigned short* __restrict__ Oh, unsigned short* __restrict__ Om, int nrows){
  int t = threadIdx.x;
  int w = t >> 6, lane = t & 63;
  int m15 = lane & 15, kg = lane >> 4;
  int rowbase = blockIdx.x*128;
  int RT = (nrows + 15) >> 4;
  int rtb = blockIdx.x*8 + w*2;

  const int SMAX = 4*NFO - 1;
  auto ldW = [&](int s, short8* d){
    size_t widx = ((size_t)s*64 + lane)*8;
    d[0] = *(const short8*)&Wh[widx];
    d[1] = *(const short8*)&Wm[widx];
  };

  f32x4 acc[2][NFO];
  #pragma unroll
  for(int mf=0;mf<2;mf++)
    #pragma unroll
    for(int nf=0;nf<NFO;nf++) acc[mf][nf] = (f32x4){0.f,0.f,0.f,0.f};

  short8 cw[2], nw[2];
  ldW(0, cw);
  ldW(1 <= SMAX ? 1 : SMAX, nw);

  for(int ks=0;ks<4;ks++){
    short8 ah[2], am[2];
    #pragma unroll
    for(int mf=0;mf<2;mf++){
      int rt = rtb + mf; if(rt >= RT) rt = RT-1;
      size_t aidx = (((size_t)rt*4 + ks)*64 + lane)*8;
      ah[mf] = *(const short8*)&Ah[aidx];
      am[mf] = *(const short8*)&Am[aidx];
    }
    #pragma unroll
    for(int nf=0;nf<NFO;nf++){
      int s = ks*NFO + nf;
      short8 pw[2];
      ldW(s+2 <= SMAX ? s+2 : SMAX, pw);
      #pragma unroll
      for(int mf=0;mf<2;mf++){
        acc[mf][nf] = __builtin_amdgcn_mfma_f32_16x16x32_bf16(ah[mf], cw[0], acc[mf][nf], 0,0,0);
        acc[mf][nf] = __builtin_amdgcn_mfma_f32_16x16x32_bf16(ah[mf], cw[1], acc[mf][nf], 0,0,0);
        acc[mf][nf] = __builtin_amdgcn_mfma_f32_16x16x32_bf16(am[mf], cw[0], acc[mf][nf], 0,0,0);
      }
      cw[0]=nw[0]; cw[1]=nw[1];
      nw[0]=pw[0]; nw[1]=pw[1];
    }
  }
  // epilogue: C/D layout col=lane&15, row=kg*4+r
  #pragma unroll
  for(int mf=0;mf<2;mf++){
    #pragma unroll
    for(int nf=0;nf<NFO;nf++){
      int gcol = nf*16 + m15;
      float bv = bias[gcol];
      #pragma unroll
      for(int r=0;r<4;r++){
        int grow = rowbase + w*32 + mf*16 + kg*4 + r;
        if(grow >= nrows) continue;
        float v = acc[mf][nf][r] + bv;
        if(GELU) v = gelu_f(v);
        if(OUTF32) Cf[(size_t)grow*(NFO*16) + gcol] = v;
        if(OUTP){
          unsigned short hh, mm2;
          split2(v, hh, mm2);
          int rt2   = grow >> 4;
          int ks2   = nf >> 1;
          int lane2 = (kg*4 + r) + 16*(m15 >> 2);
          int e2    = 4*(nf & 1) + (m15 & 3);
          size_t idx = (((size_t)rt2*4 + ks2)*64 + lane2)*8 + e2;
          Oh[idx] = hh; Om[idx] = mm2;
        }
      }
    }
  }
}

// ---------- aggregation: sequential CSR-ordered emb stream; epilogue emits bf16x2 planes
template<bool FIRST>
__global__ __launch_bounds__(256) void k_agg(const float* __restrict__ hin,
                       const float* __restrict__ embp, const float4* __restrict__ em4p,
                       const int* __restrict__ rs, const int* __restrict__ esrc,
                       const float* __restrict__ epsp,
                       unsigned short* __restrict__ Th, unsigned short* __restrict__ Tm){
  int t = threadIdx.x;
  int w = t >> 6;
  int lane = t & 63;
  int half = lane >> 5;
  int l32 = lane & 31;
  int n = blockIdx.x*4 + w;
  int d0 = l32*4;
  int rc0 = half*2, rc1 = rc0+1;
  float4 acc0 = {0.f,0.f,0.f,0.f}, acc1 = {0.f,0.f,0.f,0.f};
  int jb = rs[n], je = rs[n+1];
  if(jb < je){
    int s = esrc[jb];
    float4 ev = *(const float4*)&embp[(size_t)jb*H + d0];
    float4 m  = em4p[jb];
    float4 h0, h1;
    if(FIRST){
      h0 = *(const float4*)&hin[(size_t)s*H + d0];
      h1 = h0;
    } else {
      h0 = *(const float4*)&hin[((size_t)rc0*NN + s)*H + d0];
      h1 = *(const float4*)&hin[((size_t)rc1*NN + s)*H + d0];
    }
    for(int j=jb; j<je; j++){
      float4 ev_n = {0,0,0,0}, m_n = {0,0,0,0}, h0_n = {0,0,0,0}, h1_n = {0,0,0,0};
      if(j+1 < je){
        int s2 = esrc[j+1];
        ev_n = *(const float4*)&embp[(size_t)(j+1)*H + d0];
        m_n  = em4p[j+1];
        if(FIRST){
          h0_n = *(const float4*)&hin[(size_t)s2*H + d0];
          h1_n = h0_n;
        } else {
          h0_n = *(const float4*)&hin[((size_t)rc0*NN + s2)*H + d0];
          h1_n = *(const float4*)&hin[((size_t)rc1*NN + s2)*H + d0];
        }
      }
      float m0 = half ? m.z : m.x;
      float m1 = half ? m.w : m.y;
      if(FIRST){
        float gx = gelu_f(h0.x+ev.x);
        float gy = gelu_f(h0.y+ev.y);
        float gz = gelu_f(h0.z+ev.z);
        float gw = gelu_f(h0.w+ev.w);
        acc0.x += gx*m0; acc0.y += gy*m0; acc0.z += gz*m0; acc0.w += gw*m0;
        acc1.x += gx*m1; acc1.y += gy*m1; acc1.z += gz*m1; acc1.w += gw*m1;
      } else {
        acc0.x += gelu_f(h0.x+ev.x)*m0;
        acc0.y += gelu_f(h0.y+ev.y)*m0;
        acc0.z += gelu_f(h0.z+ev.z)*m0;
        acc0.w += gelu_f(h0.w+ev.w)*m0;
        acc1.x += gelu_f(h1.x+ev.x)*m1;
        acc1.y += gelu_f(h1.y+ev.y)*m1;
        acc1.z += gelu_f(h1.z+ev.z)*m1;
        acc1.w += gelu_f(h1.w+ev.w)*m1;
      }
      ev = ev_n; m = m_n; h0 = h0_n; h1 = h1_n;
    }
  }
  float e1 = 1.0f + epsp[0];
  int ks = d0 >> 5;
  int kgp = (d0 & 15) >> 2;
  int eb = 4*((d0 >> 4) & 1);
  #pragma unroll
  for(int p=0;p<2;p++){
    int rc = p ? rc1 : rc0;
    float4 ac = p ? acc1 : acc0;
    const float* hb = FIRST ? (hin + (size_t)n*H) : (hin + ((size_t)rc*NN + n)*H);
    float4 hv = *(const float4*)&hb[d0];
    float4 o;
    o.x = e1*hv.x + ac.x; o.y = e1*hv.y + ac.y;
    o.z = e1*hv.z + ac.z; o.w = e1*hv.w + ac.w;
    int row = rc*NN + n;
    size_t idx = (((size_t)(row >> 4)*4 + ks)*64 + (row & 15) + 16*kgp)*8 + eb;
    ushort4 hh, mm;
    split2(o.x, hh.x, mm.x);
    split2(o.y, hh.y, mm.y);
    split2(o.z, hh.z, mm.z);
    split2(o.w, hh.w, mm.w);
    *(ushort4*)&Th[idx] = hh;
    *(ushort4*)&Tm[idx] = mm;
  }
}

// ---------- deterministic masked segment mean
__global__ __launch_bounds__(64) void k_pool(const float* __restrict__ y, const float* __restrict__ nm,
                       const int* __restrict__ gs, float* __restrict__ out){
  int seg = blockIdx.x;
  int rc = seg / NG;
  int g  = seg - rc*NG;
  int c  = threadIdx.x;
  int nb = gs[g], ne = gs[g+1];
  float num = 0.f, den = 0.f;
  for(int n=nb; n<ne; n++){
    float w = nm[rc*NN + n];
    num += y[((size_t)rc*NN + n)*OUTF + c] * w;
    den += w;
  }
  out[seg*OUTF + c] = num / fmaxf(den, 1e-12f);
}

extern "C" void kernel_launch(void* const* d_in, const int* in_sizes, int n_in,
                              void* d_out, int out_size, void* d_ws, size_t ws_size,
                              hipStream_t stream){
  const float* x         = (const float*)d_in[0];
  const float* edge_attr = (const float*)d_in[1];
  const float* node_mask = (const float*)d_in[2];
  const float* bond_W    = (const float*)d_in[3];
  const float* bond_b    = (const float*)d_in[4];
  const float* epsv      = (const float*)d_in[5];
  const float* conv_W1   = (const float*)d_in[6];
  const float* conv_b1   = (const float*)d_in[7];
  const float* conv_W2   = (const float*)d_in[8];
  const float* conv_b2   = (const float*)d_in[9];
  const float* mlp_W1    = (const float*)d_in[10];
  const float* mlp_b1    = (const float*)d_in[11];
  const float* mlp_W2    = (const float*)d_in[12];
  const float* mlp_b2    = (const float*)d_in[13];
  const int*   eidx      = (const int*)d_in[14];
  const int*   batch     = (const int*)d_in[15];
  const int* srcp = eidx;
  const int* dstp = eidx + EE;

  char* p = (char*)d_ws;
  auto alloc = [&](size_t bytes)->char*{
    char* r = p; p += (bytes + 255) & ~size_t(255); return r;
  };
  float*  h    = (float*) alloc((size_t)RCN*NN*H*4);      // 20.5 MB
  float*  embp = (float*) alloc((size_t)EE*H*4);          // 81.9 MB
  float4* em4p = (float4*)alloc((size_t)EE*16);           //  2.6 MB
  float*  y    = (float*) alloc((size_t)RCN*NN*OUTF*4);   // 10.2 MB
  int*    cnt  = (int*)   alloc((size_t)NN*4);
  int*    rs   = (int*)   alloc((size_t)(NN+1)*4);
  int*    cur  = (int*)   alloc((size_t)NN*4);
  int*    eid  = (int*)   alloc((size_t)EE*4);
  int*    esrc = (int*)   alloc((size_t)EE*4);
  int*    gs   = (int*)   alloc((size_t)(NG+1)*4);
  // weight planes (bf16x2)
  unsigned short* WBh  = (unsigned short*)alloc((size_t)3*16384*2);
  unsigned short* WBm  = (unsigned short*)alloc((size_t)3*16384*2);
  unsigned short* WC1h = (unsigned short*)alloc((size_t)3*16384*2);
  unsigned short* WC1m = (unsigned short*)alloc((size_t)3*16384*2);
  unsigned short* WC2h = (unsigned short*)alloc((size_t)3*16384*2);
  unsigned short* WC2m = (unsigned short*)alloc((size_t)3*16384*2);
  unsigned short* WM1h = (unsigned short*)alloc((size_t)16384*2);
  unsigned short* WM1m = (unsigned short*)alloc((size_t)16384*2);
  unsigned short* WM2h = (unsigned short*)alloc((size_t)8192*2);
  unsigned short* WM2m = (unsigned short*)alloc((size_t)8192*2);
  // edge_attr planes (CSR-permuted, bf16x2): 82 MB
  unsigned short* EAh  = (unsigned short*)alloc((size_t)EE*H*2);
  unsigned short* EAm  = (unsigned short*)alloc((size_t)EE*H*2);
  // node activation planes (bf16x2), ping-pong TB <-> U: 41 MB
  const size_t NPB = (size_t)RCN*NN*H*2;
  unsigned short* TBh = (unsigned short*)alloc(NPB);
  unsigned short* TBm = (unsigned short*)alloc(NPB);
  unsigned short* Uh  = (unsigned short*)alloc(NPB);
  unsigned short* Um  = (unsigned short*)alloc(NPB);
  if((size_t)(p - (char*)d_ws) > ws_size) return;   // total ~239 MB (< 281 MB known-good)

  hipMemsetAsync(cnt, 0, (size_t)NN*4, stream);

  k_hist    <<<(EE+255)/256, 256, 0, stream>>>(dstp, cnt);
  k_scan    <<<1, 1024, 0, stream>>>(cnt, rs, cur);
  k_fill    <<<(EE+255)/256, 256, 0, stream>>>(dstp, cur, eid);
  k_sortcsr <<<(NN+255)/256, 256, 0, stream>>>(rs, eid, srcp, esrc);
  k_emaskp  <<<(EE+255)/256, 256, 0, stream>>>(srcp, dstp, eid, node_mask, em4p);
  k_splitA  <<<EE*32/256, 256, 0, stream>>>(edge_attr, eid, EAh, EAm);
  k_gbounds <<<1, 128, 0, stream>>>(batch, gs);
  k_splitW  <<<192, 256, 0, stream>>>(bond_W,  WBh,  WBm,  3, 128);
  k_splitW  <<<192, 256, 0, stream>>>(conv_W1, WC1h, WC1m, 3, 128);
  k_splitW  <<<192, 256, 0, stream>>>(conv_W2, WC2h, WC2m, 3, 128);
  k_splitW  <<<64,  256, 0, stream>>>(mlp_W1,  WM1h, WM1m, 1, 128);
  k_splitW  <<<32,  256, 0, stream>>>(mlp_W2,  WM2h, WM2m, 1, 64);

  const int NROWS = RCN*NN;
  const int GB_E = EE/128;             // 1250
  const int GB_N = (NROWS+127)/128;    // 313
  for(int l=0; l<3; l++){
    size_t wo = (size_t)l*16384;
    // embp = edge_attr(CSR-perm) @ bond_W + b  (fp32 out)
    k_sgemm<8,false,false,true><<<GB_E, 256, 0, stream>>>(
        EAh, EAm, WBh+wo, WBm+wo, bond_b + l*H, embp, nullptr, nullptr, EE);
    if(l == 0)
      k_agg<true ><<<NN/4, 256, 0, stream>>>(x, embp, em4p, rs, esrc, epsv + l, TBh, TBm);
    else
      k_agg<false><<<NN/4, 256, 0, stream>>>(h, embp, em4p, rs, esrc, epsv + l, TBh, TBm);
    // u = gelu(t @ W1 + b1) -> planes
    k_sgemm<8,true,true,false><<<GB_N, 256, 0, stream>>>(
        TBh, TBm, WC1h+wo, WC1m+wo, conv_b1 + l*H, nullptr, Uh, Um, NROWS);
    // h = gelu(u @ W2 + b2) -> fp32 (layers 0,1) or planes into TB (layer 2)
    if(l < 2)
      k_sgemm<8,true,false,true><<<GB_N, 256, 0, stream>>>(
          Uh, Um, WC2h+wo, WC2m+wo, conv_b2 + l*H, h, nullptr, nullptr, NROWS);
    else
      k_sgemm<8,true,true,false><<<GB_N, 256, 0, stream>>>(
          Uh, Um, WC2h+wo, WC2m+wo, conv_b2 + l*H, nullptr, TBh, TBm, NROWS);
  }
  // u2 = gelu(h_planes @ mlp_W1 + b1) -> planes (into U)
  k_sgemm<8,true,true,false><<<GB_N, 256, 0, stream>>>(
      TBh, TBm, WM1h, WM1m, mlp_b1, nullptr, Uh, Um, NROWS);
  // y = u2 @ mlp_W2 + b2 -> fp32
  k_sgemm<4,false,false,true><<<GB_N, 256, 0, stream>>>(
      Uh, Um, WM2h, WM2m, mlp_b2, y, nullptr, nullptr, NROWS);
  k_pool<<<DSEG, 64, 0, stream>>>(y, node_mask, gs, (float*)d_out);
}

// Round 11
// 689.531 us; speedup vs baseline: 1.1497x; 1.1057x over previous
//
#include <hip/hip_runtime.h>

constexpr int H    = 128;
constexpr int NN   = 10000;
constexpr int EE   = 160000;
constexpr int RCN  = 4;      // R*C
constexpr int NG   = 64;     // graphs per replica
constexpr int OUTF = 64;
constexpr int DSEG = 256;    // RCN*NG

using short8 = __attribute__((ext_vector_type(8))) short;
using f32x4  = __attribute__((ext_vector_type(4))) float;

// Exact-GELU via A&S 7.1.26 erf (|err|<=1.5e-7 abs)
__device__ __forceinline__ float gelu_f(float x){
  float z  = x*0.70710678118654752440f;
  float az = fabsf(z);
  float t  = __builtin_amdgcn_rcpf(fmaf(az, 0.3275911f, 1.0f));
  float e  = __expf(-z*z);
  float poly = fmaf(fmaf(fmaf(fmaf(1.061405429f, t, -1.453152027f),
                              t, 1.421413741f),
                         t, -0.284496736f),
                    t, 0.254829592f) * t;
  float er = fmaf(-poly, e, 1.0f);
  er = copysignf(er, z);
  return 0.5f*x*(1.0f + er);
}

// RNE 2-way split: x ~= h + m with |residual| <= ~2^-17 |x|
__device__ __forceinline__ void split2(float x, unsigned short& h, unsigned short& m){
  unsigned int u = __float_as_uint(x);
  unsigned int rh = u + 0x7FFF + ((u>>16)&1);
  h = (unsigned short)(rh>>16);
  float fh = __uint_as_float((unsigned int)h << 16);
  float r1 = x - fh;
  unsigned int u1 = __float_as_uint(r1);
  unsigned int rm = u1 + 0x7FFF + ((u1>>16)&1);
  m = (unsigned short)(rm>>16);
}

// ---------- CSR build
__global__ void k_hist(const int* __restrict__ dst, int* __restrict__ cnt){
  int e = blockIdx.x*256 + threadIdx.x;
  if(e < EE) atomicAdd(&cnt[dst[e]], 1);
}

__global__ __launch_bounds__(1024) void k_scan(const int* __restrict__ cnt,
                                               int* __restrict__ rs, int* __restrict__ cur){
  __shared__ int part[1024];
  int t = threadIdx.x;
  const int CH = 10;
  int base = t*CH;
  int s = 0;
  #pragma unroll
  for(int j=0;j<CH;j++){ int i = base+j; if(i<NN) s += cnt[i]; }
  part[t] = s;
  __syncthreads();
  for(int off=1; off<1024; off<<=1){
    int v = (t>=off) ? part[t-off] : 0;
    __syncthreads();
    part[t] += v;
    __syncthreads();
  }
  int run = (t==0) ? 0 : part[t-1];
  #pragma unroll
  for(int j=0;j<CH;j++){
    int i = base+j;
    if(i<NN){ rs[i] = run; cur[i] = run; run += cnt[i]; }
  }
  if(t == 1023) rs[NN] = part[1023];
}

__global__ void k_fill(const int* __restrict__ dst,
                       int* __restrict__ cur, int* __restrict__ eid){
  int e = blockIdx.x*256 + threadIdx.x;
  if(e >= EE) return;
  int p = atomicAdd(&cur[dst[e]], 1);
  eid[p] = e;
}

// ---------- wave-parallel bitonic sort: one wave per node (deg<=64), shfl-based
__global__ __launch_bounds__(256) void k_sortcsr(const int* __restrict__ rs, int* __restrict__ eid,
                          const int* __restrict__ src, int* __restrict__ esrc){
  int wid  = (blockIdx.x*256 + threadIdx.x) >> 6;
  int lane = threadIdx.x & 63;
  if(wid >= NN) return;
  int jb = rs[wid], je = rs[wid+1];
  int deg = je - jb;
  if(deg <= 0) return;
  if(deg == 1){
    if(lane == 0) esrc[jb] = src[eid[jb]];
    return;
  }
  if(deg <= 64){
    int v = (lane < deg) ? eid[jb + lane] : 0x7FFFFFFF;
    #pragma unroll
    for(int k=2; k<=64; k<<=1){
      #pragma unroll
      for(int j=k>>1; j>0; j>>=1){
        int o = __shfl_xor(v, j, 64);
        bool desc  = (lane & k) != 0;
        bool lower = (lane & j) == 0;
        v = ((lower != desc) ? min(v,o) : max(v,o));
      }
    }
    if(lane < deg){
      eid[jb+lane]  = v;
      esrc[jb+lane] = src[v];
    }
  } else if(lane == 0){   // essentially-never fallback (deg>64)
    for(int j=jb+1; j<je; j++){
      int v = eid[j];
      int k = j-1;
      while(k >= jb && eid[k] > v){ eid[k+1] = eid[k]; k--; }
      eid[k+1] = v;
    }
    for(int j=jb; j<je; j++) esrc[j] = src[eid[j]];
  }
}

__global__ void k_gbounds(const int* __restrict__ batch, int* __restrict__ gs){
  int g = threadIdx.x;
  if(g > NG) return;
  if(g == NG){ gs[NG] = NN; return; }
  int lo = 0, hi = NN;
  while(lo < hi){
    int mid = (lo+hi)>>1;
    if(batch[mid] < g) lo = mid+1; else hi = mid;
  }
  gs[g] = lo;
}

// ---------- edge mask in CSR-permuted order
__global__ void k_emaskp(const int* __restrict__ src, const int* __restrict__ dst,
                         const int* __restrict__ eid, const float* __restrict__ nm,
                         float4* __restrict__ em4p){
  int j = blockIdx.x*256 + threadIdx.x;
  if(j >= EE) return;
  int e = eid[j];
  int s = src[e], d = dst[e];
  float4 m;
  m.x = nm[0*NN+s]*nm[0*NN+d];
  m.y = nm[1*NN+s]*nm[1*NN+d];
  m.z = nm[2*NN+s]*nm[2*NN+d];
  m.w = nm[3*NN+s]*nm[3*NN+d];
  em4p[j] = m;
}

// ---------- split W (fp32 -> 2x bf16) into MFMA B-fragment-linear layout
__global__ void k_splitW(const float* __restrict__ W, unsigned short* __restrict__ oh,
                         unsigned short* __restrict__ om, int nmat, int N){
  int tid = blockIdx.x*256 + threadIdx.x;
  int total = nmat*128*N;
  if(tid >= total) return;
  int mat = tid / (128*N);
  int rem = tid - mat*(128*N);
  int k = rem / N;
  int n = rem - k*N;
  int NF = N >> 4;
  int ks = k >> 5, kk = k & 31;
  int nf = n >> 4;
  int lane = (n & 15) + 16*((kk & 15) >> 2);
  int e = 4*(kk >> 4) + (kk & 3);
  size_t idx = (size_t)mat*128*N + ((size_t)(ks*NF + nf)*64 + lane)*8 + e;
  unsigned short hh, mm;
  split2(W[tid], hh, mm);
  oh[idx] = hh; om[idx] = mm;
}

// ---------- split edge_attr into CSR-PERMUTED A-fragment-linear planes (bf16x2)
__global__ void k_splitA(const float* __restrict__ A, const int* __restrict__ eid,
                         unsigned short* __restrict__ oh, unsigned short* __restrict__ om){
  int tid = blockIdx.x*256 + threadIdx.x;
  if(tid >= EE*32) return;
  int j = tid >> 5, kq = tid & 31;
  int k = kq*4;
  int rsrc = eid[j];
  float4 v = *(const float4*)&A[(size_t)rsrc*H + k];
  int ks = k >> 5, kk = k & 31;
  int kg = (kk & 15) >> 2;
  int eb = 4*(kk >> 4);
  int lane = (j & 15) + 16*kg;
  size_t idx = (((size_t)(j >> 4)*4 + ks)*64 + lane)*8 + eb;
  ushort4 hh, mm;
  split2(v.x, hh.x, mm.x);
  split2(v.y, hh.y, mm.y);
  split2(v.z, hh.z, mm.z);
  split2(v.w, hh.w, mm.w);
  *(ushort4*)&oh[idx] = hh;
  *(ushort4*)&om[idx] = mm;
}

// ---------- unified split-input MFMA GEMM (bf16x2, 3 terms), no LDS, no barriers
template<int NFO, bool GELU, bool OUTP, bool OUTF32>
__global__ __launch_bounds__(256) void k_sgemm(
    const unsigned short* __restrict__ Ah, const unsigned short* __restrict__ Am,
    const unsigned short* __restrict__ Wh, const unsigned short* __restrict__ Wm,
    const float* __restrict__ bias, float* __restrict__ Cf,
    unsigned short* __restrict__ Oh, unsigned short* __restrict__ Om, int nrows){
  int t = threadIdx.x;
  int w = t >> 6, lane = t & 63;
  int m15 = lane & 15, kg = lane >> 4;
  int rowbase = blockIdx.x*128;
  int RT = (nrows + 15) >> 4;
  int rtb = blockIdx.x*8 + w*2;

  const int SMAX = 4*NFO - 1;
  auto ldW = [&](int s, short8* d){
    size_t widx = ((size_t)s*64 + lane)*8;
    d[0] = *(const short8*)&Wh[widx];
    d[1] = *(const short8*)&Wm[widx];
  };

  f32x4 acc[2][NFO];
  #pragma unroll
  for(int mf=0;mf<2;mf++)
    #pragma unroll
    for(int nf=0;nf<NFO;nf++) acc[mf][nf] = (f32x4){0.f,0.f,0.f,0.f};

  short8 cw[2], nw[2];
  ldW(0, cw);
  ldW(1 <= SMAX ? 1 : SMAX, nw);

  for(int ks=0;ks<4;ks++){
    short8 ah[2], am[2];
    #pragma unroll
    for(int mf=0;mf<2;mf++){
      int rt = rtb + mf; if(rt >= RT) rt = RT-1;
      size_t aidx = (((size_t)rt*4 + ks)*64 + lane)*8;
      ah[mf] = *(const short8*)&Ah[aidx];
      am[mf] = *(const short8*)&Am[aidx];
    }
    #pragma unroll
    for(int nf=0;nf<NFO;nf++){
      int s = ks*NFO + nf;
      short8 pw[2];
      ldW(s+2 <= SMAX ? s+2 : SMAX, pw);
      #pragma unroll
      for(int mf=0;mf<2;mf++){
        acc[mf][nf] = __builtin_amdgcn_mfma_f32_16x16x32_bf16(ah[mf], cw[0], acc[mf][nf], 0,0,0);
        acc[mf][nf] = __builtin_amdgcn_mfma_f32_16x16x32_bf16(ah[mf], cw[1], acc[mf][nf], 0,0,0);
        acc[mf][nf] = __builtin_amdgcn_mfma_f32_16x16x32_bf16(am[mf], cw[0], acc[mf][nf], 0,0,0);
      }
      cw[0]=nw[0]; cw[1]=nw[1];
      nw[0]=pw[0]; nw[1]=pw[1];
    }
  }
  // epilogue: C/D layout col=lane&15, row=kg*4+r
  #pragma unroll
  for(int mf=0;mf<2;mf++){
    #pragma unroll
    for(int nf=0;nf<NFO;nf++){
      int gcol = nf*16 + m15;
      float bv = bias[gcol];
      #pragma unroll
      for(int r=0;r<4;r++){
        int grow = rowbase + w*32 + mf*16 + kg*4 + r;
        if(grow >= nrows) continue;
        float v = acc[mf][nf][r] + bv;
        if(GELU) v = gelu_f(v);
        if(OUTF32) Cf[(size_t)grow*(NFO*16) + gcol] = v;
        if(OUTP){
          unsigned short hh, mm2;
          split2(v, hh, mm2);
          int rt2   = grow >> 4;
          int ks2   = nf >> 1;
          int lane2 = (kg*4 + r) + 16*(m15 >> 2);
          int e2    = 4*(nf & 1) + (m15 & 3);
          size_t idx = (((size_t)rt2*4 + ks2)*64 + lane2)*8 + e2;
          Oh[idx] = hh; Om[idx] = mm2;
        }
      }
    }
  }
}

// ---------- aggregation: CSR-ordered streams, 2-deep rolling pipeline
template<bool FIRST>
__global__ __launch_bounds__(256) void k_agg(const float* __restrict__ hin,
                       const float* __restrict__ embp, const float4* __restrict__ em4p,
                       const int* __restrict__ rs, const int* __restrict__ esrc,
                       const float* __restrict__ epsp,
                       unsigned short* __restrict__ Th, unsigned short* __restrict__ Tm){
  int t = threadIdx.x;
  int w = t >> 6;
  int lane = t & 63;
  int half = lane >> 5;
  int l32 = lane & 31;
  int n = blockIdx.x*4 + w;
  int d0 = l32*4;
  int rc0 = half*2, rc1 = rc0+1;
  float4 acc0 = {0.f,0.f,0.f,0.f}, acc1 = {0.f,0.f,0.f,0.f};
  int jb = rs[n], je = rs[n+1];

  float4 ev0={0,0,0,0}, h00={0,0,0,0}, h10={0,0,0,0};
  float  m00=0.f, m10=0.f;
  float4 ev1={0,0,0,0}, h01={0,0,0,0}, h11={0,0,0,0};
  float  m01=0.f, m11=0.f;

  auto ld = [&](int j, float4& ev, float4& hh0, float4& hh1, float& mm0, float& mm1){
    int s = esrc[j];
    ev = *(const float4*)&embp[(size_t)j*H + d0];
    float4 m = em4p[j];
    mm0 = half ? m.z : m.x;
    mm1 = half ? m.w : m.y;
    if(FIRST){
      hh0 = *(const float4*)&hin[(size_t)s*H + d0];
      hh1 = hh0;
    } else {
      hh0 = *(const float4*)&hin[((size_t)rc0*NN + s)*H + d0];
      hh1 = *(const float4*)&hin[((size_t)rc1*NN + s)*H + d0];
    }
  };

  if(jb < je){
    ld(jb, ev0, h00, h10, m00, m10);
    if(jb+1 < je) ld(jb+1, ev1, h01, h11, m01, m11);
    for(int j=jb; j<je; j++){
      float4 ev2={0,0,0,0}, h02={0,0,0,0}, h12={0,0,0,0};
      float  m02=0.f, m12=0.f;
      if(j+2 < je) ld(j+2, ev2, h02, h12, m02, m12);
      if(FIRST){
        float gx = gelu_f(h00.x+ev0.x);
        float gy = gelu_f(h00.y+ev0.y);
        float gz = gelu_f(h00.z+ev0.z);
        float gw = gelu_f(h00.w+ev0.w);
        acc0.x += gx*m00; acc0.y += gy*m00; acc0.z += gz*m00; acc0.w += gw*m00;
        acc1.x += gx*m10; acc1.y += gy*m10; acc1.z += gz*m10; acc1.w += gw*m10;
      } else {
        acc0.x += gelu_f(h00.x+ev0.x)*m00;
        acc0.y += gelu_f(h00.y+ev0.y)*m00;
        acc0.z += gelu_f(h00.z+ev0.z)*m00;
        acc0.w += gelu_f(h00.w+ev0.w)*m00;
        acc1.x += gelu_f(h10.x+ev0.x)*m10;
        acc1.y += gelu_f(h10.y+ev0.y)*m10;
        acc1.z += gelu_f(h10.z+ev0.z)*m10;
        acc1.w += gelu_f(h10.w+ev0.w)*m10;
      }
      ev0=ev1; h00=h01; h10=h11; m00=m01; m10=m11;
      ev1=ev2; h01=h02; h11=h12; m01=m02; m11=m12;
    }
  }
  float e1 = 1.0f + epsp[0];
  int ks = d0 >> 5;
  int kgp = (d0 & 15) >> 2;
  int eb = 4*((d0 >> 4) & 1);
  #pragma unroll
  for(int p=0;p<2;p++){
    int rc = p ? rc1 : rc0;
    float4 ac = p ? acc1 : acc0;
    const float* hb = FIRST ? (hin + (size_t)n*H) : (hin + ((size_t)rc*NN + n)*H);
    float4 hv = *(const float4*)&hb[d0];
    float4 o;
    o.x = e1*hv.x + ac.x; o.y = e1*hv.y + ac.y;
    o.z = e1*hv.z + ac.z; o.w = e1*hv.w + ac.w;
    int row = rc*NN + n;
    size_t idx = (((size_t)(row >> 4)*4 + ks)*64 + (row & 15) + 16*kgp)*8 + eb;
    ushort4 hh, mm;
    split2(o.x, hh.x, mm.x);
    split2(o.y, hh.y, mm.y);
    split2(o.z, hh.z, mm.z);
    split2(o.w, hh.w, mm.w);
    *(ushort4*)&Th[idx] = hh;
    *(ushort4*)&Tm[idx] = mm;
  }
}

// ---------- deterministic masked segment mean
__global__ __launch_bounds__(64) void k_pool(const float* __restrict__ y, const float* __restrict__ nm,
                       const int* __restrict__ gs, float* __restrict__ out){
  int seg = blockIdx.x;
  int rc = seg / NG;
  int g  = seg - rc*NG;
  int c  = threadIdx.x;
  int nb = gs[g], ne = gs[g+1];
  float num = 0.f, den = 0.f;
  for(int n=nb; n<ne; n++){
    float w = nm[rc*NN + n];
    num += y[((size_t)rc*NN + n)*OUTF + c] * w;
    den += w;
  }
  out[seg*OUTF + c] = num / fmaxf(den, 1e-12f);
}

extern "C" void kernel_launch(void* const* d_in, const int* in_sizes, int n_in,
                              void* d_out, int out_size, void* d_ws, size_t ws_size,
                              hipStream_t stream){
  const float* x         = (const float*)d_in[0];
  const float* edge_attr = (const float*)d_in[1];
  const float* node_mask = (const float*)d_in[2];
  const float* bond_W    = (const float*)d_in[3];
  const float* bond_b    = (const float*)d_in[4];
  const float* epsv      = (const float*)d_in[5];
  const float* conv_W1   = (const float*)d_in[6];
  const float* conv_b1   = (const float*)d_in[7];
  const float* conv_W2   = (const float*)d_in[8];
  const float* conv_b2   = (const float*)d_in[9];
  const float* mlp_W1    = (const float*)d_in[10];
  const float* mlp_b1    = (const float*)d_in[11];
  const float* mlp_W2    = (const float*)d_in[12];
  const float* mlp_b2    = (const float*)d_in[13];
  const int*   eidx      = (const int*)d_in[14];
  const int*   batch     = (const int*)d_in[15];
  const int* srcp = eidx;
  const int* dstp = eidx + EE;

  char* p = (char*)d_ws;
  auto alloc = [&](size_t bytes)->char*{
    char* r = p; p += (bytes + 255) & ~size_t(255); return r;
  };
  float*  h    = (float*) alloc((size_t)RCN*NN*H*4);      // 20.5 MB
  float*  embp = (float*) alloc((size_t)EE*H*4);          // 81.9 MB
  float4* em4p = (float4*)alloc((size_t)EE*16);           //  2.6 MB
  float*  y    = (float*) alloc((size_t)RCN*NN*OUTF*4);   // 10.2 MB
  int*    cnt  = (int*)   alloc((size_t)NN*4);
  int*    rs   = (int*)   alloc((size_t)(NN+1)*4);
  int*    cur  = (int*)   alloc((size_t)NN*4);
  int*    eid  = (int*)   alloc((size_t)EE*4);
  int*    esrc = (int*)   alloc((size_t)EE*4);
  int*    gs   = (int*)   alloc((size_t)(NG+1)*4);
  // weight planes (bf16x2)
  unsigned short* WBh  = (unsigned short*)alloc((size_t)3*16384*2);
  unsigned short* WBm  = (unsigned short*)alloc((size_t)3*16384*2);
  unsigned short* WC1h = (unsigned short*)alloc((size_t)3*16384*2);
  unsigned short* WC1m = (unsigned short*)alloc((size_t)3*16384*2);
  unsigned short* WC2h = (unsigned short*)alloc((size_t)3*16384*2);
  unsigned short* WC2m = (unsigned short*)alloc((size_t)3*16384*2);
  unsigned short* WM1h = (unsigned short*)alloc((size_t)16384*2);
  unsigned short* WM1m = (unsigned short*)alloc((size_t)16384*2);
  unsigned short* WM2h = (unsigned short*)alloc((size_t)8192*2);
  unsigned short* WM2m = (unsigned short*)alloc((size_t)8192*2);
  // edge_attr planes (CSR-permuted, bf16x2): 82 MB
  unsigned short* EAh  = (unsigned short*)alloc((size_t)EE*H*2);
  unsigned short* EAm  = (unsigned short*)alloc((size_t)EE*H*2);
  // node activation planes (bf16x2), ping-pong TB <-> U: 41 MB
  const size_t NPB = (size_t)RCN*NN*H*2;
  unsigned short* TBh = (unsigned short*)alloc(NPB);
  unsigned short* TBm = (unsigned short*)alloc(NPB);
  unsigned short* Uh  = (unsigned short*)alloc(NPB);
  unsigned short* Um  = (unsigned short*)alloc(NPB);
  if((size_t)(p - (char*)d_ws) > ws_size) return;   // total ~239 MB

  hipMemsetAsync(cnt, 0, (size_t)NN*4, stream);

  k_hist    <<<(EE+255)/256, 256, 0, stream>>>(dstp, cnt);
  k_scan    <<<1, 1024, 0, stream>>>(cnt, rs, cur);
  k_fill    <<<(EE+255)/256, 256, 0, stream>>>(dstp, cur, eid);
  k_sortcsr <<<(NN*64+255)/256, 256, 0, stream>>>(rs, eid, srcp, esrc);
  k_emaskp  <<<(EE+255)/256, 256, 0, stream>>>(srcp, dstp, eid, node_mask, em4p);
  k_splitA  <<<EE*32/256, 256, 0, stream>>>(edge_attr, eid, EAh, EAm);
  k_gbounds <<<1, 128, 0, stream>>>(batch, gs);
  k_splitW  <<<192, 256, 0, stream>>>(bond_W,  WBh,  WBm,  3, 128);
  k_splitW  <<<192, 256, 0, stream>>>(conv_W1, WC1h, WC1m, 3, 128);
  k_splitW  <<<192, 256, 0, stream>>>(conv_W2, WC2h, WC2m, 3, 128);
  k_splitW  <<<64,  256, 0, stream>>>(mlp_W1,  WM1h, WM1m, 1, 128);
  k_splitW  <<<32,  256, 0, stream>>>(mlp_W2,  WM2h, WM2m, 1, 64);

  const int NROWS = RCN*NN;
  const int GB_E = EE/128;             // 1250
  const int GB_N = (NROWS+127)/128;    // 313
  for(int l=0; l<3; l++){
    size_t wo = (size_t)l*16384;
    // embp = edge_attr(CSR-perm) @ bond_W + b  (fp32 out)
    k_sgemm<8,false,false,true><<<GB_E, 256, 0, stream>>>(
        EAh, EAm, WBh+wo, WBm+wo, bond_b + l*H, embp, nullptr, nullptr, EE);
    if(l == 0)
      k_agg<true ><<<NN/4, 256, 0, stream>>>(x, embp, em4p, rs, esrc, epsv + l, TBh, TBm);
    else
      k_agg<false><<<NN/4, 256, 0, stream>>>(h, embp, em4p, rs, esrc, epsv + l, TBh, TBm);
    // u = gelu(t @ W1 + b1) -> planes
    k_sgemm<8,true,true,false><<<GB_N, 256, 0, stream>>>(
        TBh, TBm, WC1h+wo, WC1m+wo, conv_b1 + l*H, nullptr, Uh, Um, NROWS);
    // h = gelu(u @ W2 + b2) -> fp32 (layers 0,1) or planes into TB (layer 2)
    if(l < 2)
      k_sgemm<8,true,false,true><<<GB_N, 256, 0, stream>>>(
          Uh, Um, WC2h+wo, WC2m+wo, conv_b2 + l*H, h, nullptr, nullptr, NROWS);
    else
      k_sgemm<8,true,true,false><<<GB_N, 256, 0, stream>>>(
          Uh, Um, WC2h+wo, WC2m+wo, conv_b2 + l*H, nullptr, TBh, TBm, NROWS);
  }
  // u2 = gelu(h_planes @ mlp_W1 + b1) -> planes (into U)
  k_sgemm<8,true,true,false><<<GB_N, 256, 0, stream>>>(
      TBh, TBm, WM1h, WM1m, mlp_b1, nullptr, Uh, Um, NROWS);
  // y = u2 @ mlp_W2 + b2 -> fp32
  k_sgemm<4,false,false,true><<<GB_N, 256, 0, stream>>>(
      Uh, Um, WM2h, WM2m, mlp_b2, y, nullptr, nullptr, NROWS);
  k_pool<<<DSEG, 64, 0, stream>>>(y, node_mask, gs, (float*)d_out);
}

// Round 12
// 652.234 us; speedup vs baseline: 1.2155x; 1.0572x over previous
//
#include <hip/hip_runtime.h>

constexpr int H    = 128;
constexpr int NN   = 10000;
constexpr int EE   = 160000;
constexpr int RCN  = 4;      // R*C
constexpr int NG   = 64;     // graphs per replica
constexpr int OUTF = 64;
constexpr int DSEG = 256;    // RCN*NG

using short8 = __attribute__((ext_vector_type(8))) short;
using f32x4  = __attribute__((ext_vector_type(4))) float;

// Exact-GELU via A&S 7.1.26 erf (|err|<=1.5e-7 abs)
__device__ __forceinline__ float gelu_f(float x){
  float z  = x*0.70710678118654752440f;
  float az = fabsf(z);
  float t  = __builtin_amdgcn_rcpf(fmaf(az, 0.3275911f, 1.0f));
  float e  = __expf(-z*z);
  float poly = fmaf(fmaf(fmaf(fmaf(1.061405429f, t, -1.453152027f),
                              t, 1.421413741f),
                         t, -0.284496736f),
                    t, 0.254829592f) * t;
  float er = fmaf(-poly, e, 1.0f);
  er = copysignf(er, z);
  return 0.5f*x*(1.0f + er);
}

// RNE 2-way split: x ~= h + m with |residual| <= ~2^-17 |x|
__device__ __forceinline__ void split2(float x, unsigned short& h, unsigned short& m){
  unsigned int u = __float_as_uint(x);
  unsigned int rh = u + 0x7FFF + ((u>>16)&1);
  h = (unsigned short)(rh>>16);
  float fh = __uint_as_float((unsigned int)h << 16);
  float r1 = x - fh;
  unsigned int u1 = __float_as_uint(r1);
  unsigned int rm = u1 + 0x7FFF + ((u1>>16)&1);
  m = (unsigned short)(rm>>16);
}

// ---------- CSR build
__global__ void k_hist(const int* __restrict__ dst, int* __restrict__ cnt){
  int e = blockIdx.x*256 + threadIdx.x;
  if(e < EE) atomicAdd(&cnt[dst[e]], 1);
}

__global__ __launch_bounds__(1024) void k_scan(const int* __restrict__ cnt,
                                               int* __restrict__ rs, int* __restrict__ cur){
  __shared__ int part[1024];
  int t = threadIdx.x;
  const int CH = 10;
  int base = t*CH;
  int s = 0;
  #pragma unroll
  for(int j=0;j<CH;j++){ int i = base+j; if(i<NN) s += cnt[i]; }
  part[t] = s;
  __syncthreads();
  for(int off=1; off<1024; off<<=1){
    int v = (t>=off) ? part[t-off] : 0;
    __syncthreads();
    part[t] += v;
    __syncthreads();
  }
  int run = (t==0) ? 0 : part[t-1];
  #pragma unroll
  for(int j=0;j<CH;j++){
    int i = base+j;
    if(i<NN){ rs[i] = run; cur[i] = run; run += cnt[i]; }
  }
  if(t == 1023) rs[NN] = part[1023];
}

__global__ void k_fill(const int* __restrict__ dst,
                       int* __restrict__ cur, int* __restrict__ eid){
  int e = blockIdx.x*256 + threadIdx.x;
  if(e >= EE) return;
  int p = atomicAdd(&cur[dst[e]], 1);
  eid[p] = e;
}

// ---------- wave-parallel bitonic sort: one wave per node (deg<=64), shfl-based
__global__ __launch_bounds__(256) void k_sortcsr(const int* __restrict__ rs, int* __restrict__ eid,
                          const int* __restrict__ src, int* __restrict__ esrc){
  int wid  = (blockIdx.x*256 + threadIdx.x) >> 6;
  int lane = threadIdx.x & 63;
  if(wid >= NN) return;
  int jb = rs[wid], je = rs[wid+1];
  int deg = je - jb;
  if(deg <= 0) return;
  if(deg == 1){
    if(lane == 0) esrc[jb] = src[eid[jb]];
    return;
  }
  if(deg <= 64){
    int v = (lane < deg) ? eid[jb + lane] : 0x7FFFFFFF;
    #pragma unroll
    for(int k=2; k<=64; k<<=1){
      #pragma unroll
      for(int j=k>>1; j>0; j>>=1){
        int o = __shfl_xor(v, j, 64);
        bool desc  = (lane & k) != 0;
        bool lower = (lane & j) == 0;
        v = ((lower != desc) ? min(v,o) : max(v,o));
      }
    }
    if(lane < deg){
      eid[jb+lane]  = v;
      esrc[jb+lane] = src[v];
    }
  } else if(lane == 0){
    for(int j=jb+1; j<je; j++){
      int v = eid[j];
      int k = j-1;
      while(k >= jb && eid[k] > v){ eid[k+1] = eid[k]; k--; }
      eid[k+1] = v;
    }
    for(int j=jb; j<je; j++) esrc[j] = src[eid[j]];
  }
}

__global__ void k_gbounds(const int* __restrict__ batch, int* __restrict__ gs){
  int g = threadIdx.x;
  if(g > NG) return;
  if(g == NG){ gs[NG] = NN; return; }
  int lo = 0, hi = NN;
  while(lo < hi){
    int mid = (lo+hi)>>1;
    if(batch[mid] < g) lo = mid+1; else hi = mid;
  }
  gs[g] = lo;
}

// ---------- edge mask in CSR-permuted order
__global__ void k_emaskp(const int* __restrict__ src, const int* __restrict__ dst,
                         const int* __restrict__ eid, const float* __restrict__ nm,
                         float4* __restrict__ em4p){
  int j = blockIdx.x*256 + threadIdx.x;
  if(j >= EE) return;
  int e = eid[j];
  int s = src[e], d = dst[e];
  float4 m;
  m.x = nm[0*NN+s]*nm[0*NN+d];
  m.y = nm[1*NN+s]*nm[1*NN+d];
  m.z = nm[2*NN+s]*nm[2*NN+d];
  m.w = nm[3*NN+s]*nm[3*NN+d];
  em4p[j] = m;
}

// ---------- split W (fp32 -> 2x bf16) into MFMA B-fragment-linear layout (unchanged)
__global__ void k_splitW(const float* __restrict__ W, unsigned short* __restrict__ oh,
                         unsigned short* __restrict__ om, int nmat, int N){
  int tid = blockIdx.x*256 + threadIdx.x;
  int total = nmat*128*N;
  if(tid >= total) return;
  int mat = tid / (128*N);
  int rem = tid - mat*(128*N);
  int k = rem / N;
  int n = rem - k*N;
  int NF = N >> 4;
  int ks = k >> 5, kk = k & 31;
  int nf = n >> 4;
  int lane = (n & 15) + 16*((kk & 15) >> 2);
  int e = 4*(kk >> 4) + (kk & 3);
  size_t idx = (size_t)mat*128*N + ((size_t)(ks*NF + nf)*64 + lane)*8 + e;
  unsigned short hh, mm;
  split2(W[tid], hh, mm);
  oh[idx] = hh; om[idx] = mm;
}

// ---------- split edge_attr into CSR-PERMUTED ROW-MAJOR planes (coalesced writes)
__global__ void k_splitA(const float* __restrict__ A, const int* __restrict__ eid,
                         unsigned short* __restrict__ oh, unsigned short* __restrict__ om){
  int tid = blockIdx.x*256 + threadIdx.x;
  if(tid >= EE*32) return;
  int j = tid >> 5, kq = tid & 31;
  int k = kq*4;
  int rsrc = eid[j];
  float4 v = *(const float4*)&A[(size_t)rsrc*H + k];
  ushort4 hh, mm;
  split2(v.x, hh.x, mm.x);
  split2(v.y, hh.y, mm.y);
  split2(v.z, hh.z, mm.z);
  split2(v.w, hh.w, mm.w);
  size_t idx = (size_t)j*H + k;
  *(ushort4*)&oh[idx] = hh;
  *(ushort4*)&om[idx] = mm;
}

// ---------- unified split-input MFMA GEMM (bf16x2, 3 terms), no LDS, no barriers
// A planes are ROW-MAJOR [row][128]; W planes frag-linear.
// A-frag for (row-tile, ks): lane=(row&15)+16*kg; elems 0-3 = k(ks*32+4kg+0..3),
// elems 4-7 = +16.
template<int NFO, bool GELU, bool OUTP, bool OUTF32>
__global__ __launch_bounds__(256) void k_sgemm(
    const unsigned short* __restrict__ Ah, const unsigned short* __restrict__ Am,
    const unsigned short* __restrict__ Wh, const unsigned short* __restrict__ Wm,
    const float* __restrict__ bias, float* __restrict__ Cf,
    unsigned short* __restrict__ Oh, unsigned short* __restrict__ Om, int nrows){
  int t = threadIdx.x;
  int w = t >> 6, lane = t & 63;
  int m15 = lane & 15, kg = lane >> 4;
  int rowbase = blockIdx.x*128;

  const int SMAX = 4*NFO - 1;
  auto ldW = [&](int s, short8* d){
    size_t widx = ((size_t)s*64 + lane)*8;
    d[0] = *(const short8*)&Wh[widx];
    d[1] = *(const short8*)&Wm[widx];
  };

  // clamped source rows for the two m-fragments
  int arow[2];
  #pragma unroll
  for(int mf=0;mf<2;mf++){
    int r = rowbase + w*32 + mf*16 + m15;
    arow[mf] = (r < nrows) ? r : (nrows-1);
  }

  f32x4 acc[2][NFO];
  #pragma unroll
  for(int mf=0;mf<2;mf++)
    #pragma unroll
    for(int nf=0;nf<NFO;nf++) acc[mf][nf] = (f32x4){0.f,0.f,0.f,0.f};

  short8 cw[2], nw[2];
  ldW(0, cw);
  ldW(1 <= SMAX ? 1 : SMAX, nw);

  for(int ks=0;ks<4;ks++){
    short8 ah[2], am[2];
    #pragma unroll
    for(int mf=0;mf<2;mf++){
      size_t base = (size_t)arow[mf]*H + ks*32 + kg*4;
      ushort4 hlo = *(const ushort4*)&Ah[base];
      ushort4 hhi = *(const ushort4*)&Ah[base + 16];
      ushort4 mlo = *(const ushort4*)&Am[base];
      ushort4 mhi = *(const ushort4*)&Am[base + 16];
      ah[mf] = (short8){(short)hlo.x,(short)hlo.y,(short)hlo.z,(short)hlo.w,
                        (short)hhi.x,(short)hhi.y,(short)hhi.z,(short)hhi.w};
      am[mf] = (short8){(short)mlo.x,(short)mlo.y,(short)mlo.z,(short)mlo.w,
                        (short)mhi.x,(short)mhi.y,(short)mhi.z,(short)mhi.w};
    }
    #pragma unroll
    for(int nf=0;nf<NFO;nf++){
      int s = ks*NFO + nf;
      short8 pw[2];
      ldW(s+2 <= SMAX ? s+2 : SMAX, pw);
      #pragma unroll
      for(int mf=0;mf<2;mf++){
        acc[mf][nf] = __builtin_amdgcn_mfma_f32_16x16x32_bf16(ah[mf], cw[0], acc[mf][nf], 0,0,0);
        acc[mf][nf] = __builtin_amdgcn_mfma_f32_16x16x32_bf16(ah[mf], cw[1], acc[mf][nf], 0,0,0);
        acc[mf][nf] = __builtin_amdgcn_mfma_f32_16x16x32_bf16(am[mf], cw[0], acc[mf][nf], 0,0,0);
      }
      cw[0]=nw[0]; cw[1]=nw[1];
      nw[0]=pw[0]; nw[1]=pw[1];
    }
  }
  // epilogue: C/D layout col=lane&15, row=kg*4+r
  #pragma unroll
  for(int mf=0;mf<2;mf++){
    #pragma unroll
    for(int nf=0;nf<NFO;nf++){
      int gcol = nf*16 + m15;
      float bv = bias[gcol];
      #pragma unroll
      for(int r=0;r<4;r++){
        int grow = rowbase + w*32 + mf*16 + kg*4 + r;
        if(grow >= nrows) continue;
        float v = acc[mf][nf][r] + bv;
        if(GELU) v = gelu_f(v);
        if(OUTF32) Cf[(size_t)grow*(NFO*16) + gcol] = v;
        if(OUTP){
          unsigned short hh, mm2;
          split2(v, hh, mm2);
          size_t idx = (size_t)grow*(NFO*16) + gcol;
          Oh[idx] = hh; Om[idx] = mm2;
        }
      }
    }
  }
}

// ---------- aggregation: CSR-ordered streams, 3-deep rolling pipeline,
// row-major coalesced plane writes
template<bool FIRST>
__global__ __launch_bounds__(256) void k_agg(const float* __restrict__ hin,
                       const float* __restrict__ embp, const float4* __restrict__ em4p,
                       const int* __restrict__ rs, const int* __restrict__ esrc,
                       const float* __restrict__ epsp,
                       unsigned short* __restrict__ Th, unsigned short* __restrict__ Tm){
  int t = threadIdx.x;
  int w = t >> 6;
  int lane = t & 63;
  int half = lane >> 5;
  int l32 = lane & 31;
  int n = blockIdx.x*4 + w;
  int d0 = l32*4;
  int rc0 = half*2, rc1 = rc0+1;
  float4 acc0 = {0.f,0.f,0.f,0.f}, acc1 = {0.f,0.f,0.f,0.f};
  int jb = rs[n], je = rs[n+1];

  float4 evs[3], h0s[3], h1s[3];
  float  m0s[3], m1s[3];

  auto ld = [&](int j, int slot){
    int s = esrc[j];
    evs[slot] = *(const float4*)&embp[(size_t)j*H + d0];
    float4 m = em4p[j];
    m0s[slot] = half ? m.z : m.x;
    m1s[slot] = half ? m.w : m.y;
    if(FIRST){
      h0s[slot] = *(const float4*)&hin[(size_t)s*H + d0];
      h1s[slot] = h0s[slot];
    } else {
      h0s[slot] = *(const float4*)&hin[((size_t)rc0*NN + s)*H + d0];
      h1s[slot] = *(const float4*)&hin[((size_t)rc1*NN + s)*H + d0];
    }
  };

  if(jb < je){
    ld(jb, 0);
    if(jb+1 < je) ld(jb+1, 1);
    if(jb+2 < je) ld(jb+2, 2);
    for(int j=jb; j<je; j++){
      float4 ev0 = evs[0], h00 = h0s[0], h10 = h1s[0];
      float  m00 = m0s[0], m10 = m1s[0];
      // shift pipeline
      evs[0]=evs[1]; h0s[0]=h0s[1]; h1s[0]=h1s[1]; m0s[0]=m0s[1]; m1s[0]=m1s[1];
      evs[1]=evs[2]; h0s[1]=h0s[2]; h1s[1]=h1s[2]; m0s[1]=m0s[2]; m1s[1]=m1s[2];
      if(j+3 < je) ld(j+3, 2);
      if(FIRST){
        float gx = gelu_f(h00.x+ev0.x);
        float gy = gelu_f(h00.y+ev0.y);
        float gz = gelu_f(h00.z+ev0.z);
        float gw = gelu_f(h00.w+ev0.w);
        acc0.x += gx*m00; acc0.y += gy*m00; acc0.z += gz*m00; acc0.w += gw*m00;
        acc1.x += gx*m10; acc1.y += gy*m10; acc1.z += gz*m10; acc1.w += gw*m10;
      } else {
        acc0.x += gelu_f(h00.x+ev0.x)*m00;
        acc0.y += gelu_f(h00.y+ev0.y)*m00;
        acc0.z += gelu_f(h00.z+ev0.z)*m00;
        acc0.w += gelu_f(h00.w+ev0.w)*m00;
        acc1.x += gelu_f(h10.x+ev0.x)*m10;
        acc1.y += gelu_f(h10.y+ev0.y)*m10;
        acc1.z += gelu_f(h10.z+ev0.z)*m10;
        acc1.w += gelu_f(h10.w+ev0.w)*m10;
      }
    }
  }
  float e1 = 1.0f + epsp[0];
  #pragma unroll
  for(int p=0;p<2;p++){
    int rc = p ? rc1 : rc0;
    float4 ac = p ? acc1 : acc0;
    const float* hb = FIRST ? (hin + (size_t)n*H) : (hin + ((size_t)rc*NN + n)*H);
    float4 hv = *(const float4*)&hb[d0];
    float4 o;
    o.x = e1*hv.x + ac.x; o.y = e1*hv.y + ac.y;
    o.z = e1*hv.z + ac.z; o.w = e1*hv.w + ac.w;
    int row = rc*NN + n;
    ushort4 hh, mm;
    split2(o.x, hh.x, mm.x);
    split2(o.y, hh.y, mm.y);
    split2(o.z, hh.z, mm.z);
    split2(o.w, hh.w, mm.w);
    size_t idx = (size_t)row*H + d0;
    *(ushort4*)&Th[idx] = hh;   // 32 lanes x 8B = 256B contiguous per row
    *(ushort4*)&Tm[idx] = mm;
  }
}

// ---------- deterministic masked segment mean
__global__ __launch_bounds__(64) void k_pool(const float* __restrict__ y, const float* __restrict__ nm,
                       const int* __restrict__ gs, float* __restrict__ out){
  int seg = blockIdx.x;
  int rc = seg / NG;
  int g  = seg - rc*NG;
  int c  = threadIdx.x;
  int nb = gs[g], ne = gs[g+1];
  float num = 0.f, den = 0.f;
  for(int n=nb; n<ne; n++){
    float w = nm[rc*NN + n];
    num += y[((size_t)rc*NN + n)*OUTF + c] * w;
    den += w;
  }
  out[seg*OUTF + c] = num / fmaxf(den, 1e-12f);
}

extern "C" void kernel_launch(void* const* d_in, const int* in_sizes, int n_in,
                              void* d_out, int out_size, void* d_ws, size_t ws_size,
                              hipStream_t stream){
  const float* x         = (const float*)d_in[0];
  const float* edge_attr = (const float*)d_in[1];
  const float* node_mask = (const float*)d_in[2];
  const float* bond_W    = (const float*)d_in[3];
  const float* bond_b    = (const float*)d_in[4];
  const float* epsv      = (const float*)d_in[5];
  const float* conv_W1   = (const float*)d_in[6];
  const float* conv_b1   = (const float*)d_in[7];
  const float* conv_W2   = (const float*)d_in[8];
  const float* conv_b2   = (const float*)d_in[9];
  const float* mlp_W1    = (const float*)d_in[10];
  const float* mlp_b1    = (const float*)d_in[11];
  const float* mlp_W2    = (const float*)d_in[12];
  const float* mlp_b2    = (const float*)d_in[13];
  const int*   eidx      = (const int*)d_in[14];
  const int*   batch     = (const int*)d_in[15];
  const int* srcp = eidx;
  const int* dstp = eidx + EE;

  char* p = (char*)d_ws;
  auto alloc = [&](size_t bytes)->char*{
    char* r = p; p += (bytes + 255) & ~size_t(255); return r;
  };
  float*  h    = (float*) alloc((size_t)RCN*NN*H*4);      // 20.5 MB
  float*  embp = (float*) alloc((size_t)EE*H*4);          // 81.9 MB
  float4* em4p = (float4*)alloc((size_t)EE*16);           //  2.6 MB
  float*  y    = (float*) alloc((size_t)RCN*NN*OUTF*4);   // 10.2 MB
  int*    cnt  = (int*)   alloc((size_t)NN*4);
  int*    rs   = (int*)   alloc((size_t)(NN+1)*4);
  int*    cur  = (int*)   alloc((size_t)NN*4);
  int*    eid  = (int*)   alloc((size_t)EE*4);
  int*    esrc = (int*)   alloc((size_t)EE*4);
  int*    gs   = (int*)   alloc((size_t)(NG+1)*4);
  // weight planes (bf16x2, frag-linear)
  unsigned short* WBh  = (unsigned short*)alloc((size_t)3*16384*2);
  unsigned short* WBm  = (unsigned short*)alloc((size_t)3*16384*2);
  unsigned short* WC1h = (unsigned short*)alloc((size_t)3*16384*2);
  unsigned short* WC1m = (unsigned short*)alloc((size_t)3*16384*2);
  unsigned short* WC2h = (unsigned short*)alloc((size_t)3*16384*2);
  unsigned short* WC2m = (unsigned short*)alloc((size_t)3*16384*2);
  unsigned short* WM1h = (unsigned short*)alloc((size_t)16384*2);
  unsigned short* WM1m = (unsigned short*)alloc((size_t)16384*2);
  unsigned short* WM2h = (unsigned short*)alloc((size_t)8192*2);
  unsigned short* WM2m = (unsigned short*)alloc((size_t)8192*2);
  // edge_attr planes (CSR-permuted, row-major bf16x2): 82 MB
  unsigned short* EAh  = (unsigned short*)alloc((size_t)EE*H*2);
  unsigned short* EAm  = (unsigned short*)alloc((size_t)EE*H*2);
  // node activation planes (row-major bf16x2), ping-pong TB <-> U: 41 MB
  const size_t NPB = (size_t)RCN*NN*H*2;
  unsigned short* TBh = (unsigned short*)alloc(NPB);
  unsigned short* TBm = (unsigned short*)alloc(NPB);
  unsigned short* Uh  = (unsigned short*)alloc(NPB);
  unsigned short* Um  = (unsigned short*)alloc(NPB);
  if((size_t)(p - (char*)d_ws) > ws_size) return;   // total ~239 MB

  hipMemsetAsync(cnt, 0, (size_t)NN*4, stream);

  k_hist    <<<(EE+255)/256, 256, 0, stream>>>(dstp, cnt);
  k_scan    <<<1, 1024, 0, stream>>>(cnt, rs, cur);
  k_fill    <<<(EE+255)/256, 256, 0, stream>>>(dstp, cur, eid);
  k_sortcsr <<<(NN*64+255)/256, 256, 0, stream>>>(rs, eid, srcp, esrc);
  k_emaskp  <<<(EE+255)/256, 256, 0, stream>>>(srcp, dstp, eid, node_mask, em4p);
  k_splitA  <<<EE*32/256, 256, 0, stream>>>(edge_attr, eid, EAh, EAm);
  k_gbounds <<<1, 128, 0, stream>>>(batch, gs);
  k_splitW  <<<192, 256, 0, stream>>>(bond_W,  WBh,  WBm,  3, 128);
  k_splitW  <<<192, 256, 0, stream>>>(conv_W1, WC1h, WC1m, 3, 128);
  k_splitW  <<<192, 256, 0, stream>>>(conv_W2, WC2h, WC2m, 3, 128);
  k_splitW  <<<64,  256, 0, stream>>>(mlp_W1,  WM1h, WM1m, 1, 128);
  k_splitW  <<<32,  256, 0, stream>>>(mlp_W2,  WM2h, WM2m, 1, 64);

  const int NROWS = RCN*NN;
  const int GB_E = EE/128;             // 1250
  const int GB_N = (NROWS+127)/128;    // 313
  for(int l=0; l<3; l++){
    size_t wo = (size_t)l*16384;
    // embp = edge_attr(CSR-perm) @ bond_W + b  (fp32 out)
    k_sgemm<8,false,false,true><<<GB_E, 256, 0, stream>>>(
        EAh, EAm, WBh+wo, WBm+wo, bond_b + l*H, embp, nullptr, nullptr, EE);
    if(l == 0)
      k_agg<true ><<<NN/4, 256, 0, stream>>>(x, embp, em4p, rs, esrc, epsv + l, TBh, TBm);
    else
      k_agg<false><<<NN/4, 256, 0, stream>>>(h, embp, em4p, rs, esrc, epsv + l, TBh, TBm);
    // u = gelu(t @ W1 + b1) -> planes
    k_sgemm<8,true,true,false><<<GB_N, 256, 0, stream>>>(
        TBh, TBm, WC1h+wo, WC1m+wo, conv_b1 + l*H, nullptr, Uh, Um, NROWS);
    // h = gelu(u @ W2 + b2) -> fp32 (layers 0,1) or planes into TB (layer 2)
    if(l < 2)
      k_sgemm<8,true,false,true><<<GB_N, 256, 0, stream>>>(
          Uh, Um, WC2h+wo, WC2m+wo, conv_b2 + l*H, h, nullptr, nullptr, NROWS);
    else
      k_sgemm<8,true,true,false><<<GB_N, 256, 0, stream>>>(
          Uh, Um, WC2h+wo, WC2m+wo, conv_b2 + l*H, nullptr, TBh, TBm, NROWS);
  }
  // u2 = gelu(h_planes @ mlp_W1 + b1) -> planes (into U)
  k_sgemm<8,true,true,false><<<GB_N, 256, 0, stream>>>(
      TBh, TBm, WM1h, WM1m, mlp_b1, nullptr, Uh, Um, NROWS);
  // y = u2 @ mlp_W2 + b2 -> fp32
  k_sgemm<4,false,false,true><<<GB_N, 256, 0, stream>>>(
      Uh, Um, WM2h, WM2m, mlp_b2, y, nullptr, nullptr, NROWS);
  k_pool<<<DSEG, 64, 0, stream>>>(y, node_mask, gs, (float*)d_out);
}

// Round 13
// 613.330 us; speedup vs baseline: 1.2926x; 1.0634x over previous
//
#include <hip/hip_runtime.h>

constexpr int H    = 128;
constexpr int NN   = 10000;
constexpr int EE   = 160000;
constexpr int RCN  = 4;      // R*C
constexpr int NG   = 64;     // graphs per replica
constexpr int OUTF = 64;
constexpr int DSEG = 256;    // RCN*NG

using short8 = __attribute__((ext_vector_type(8))) short;
using f32x4  = __attribute__((ext_vector_type(4))) float;

// Exact-GELU via A&S 7.1.26 erf (|err|<=1.5e-7 abs)
__device__ __forceinline__ float gelu_f(float x){
  float z  = x*0.70710678118654752440f;
  float az = fabsf(z);
  float t  = __builtin_amdgcn_rcpf(fmaf(az, 0.3275911f, 1.0f));
  float e  = __expf(-z*z);
  float poly = fmaf(fmaf(fmaf(fmaf(1.061405429f, t, -1.453152027f),
                              t, 1.421413741f),
                         t, -0.284496736f),
                    t, 0.254829592f) * t;
  float er = fmaf(-poly, e, 1.0f);
  er = copysignf(er, z);
  return 0.5f*x*(1.0f + er);
}

// RNE 2-way split
__device__ __forceinline__ void split2(float x, unsigned short& h, unsigned short& m){
  unsigned int u = __float_as_uint(x);
  unsigned int rh = u + 0x7FFF + ((u>>16)&1);
  h = (unsigned short)(rh>>16);
  float fh = __uint_as_float((unsigned int)h << 16);
  float r1 = x - fh;
  unsigned int u1 = __float_as_uint(r1);
  unsigned int rm = u1 + 0x7FFF + ((u1>>16)&1);
  m = (unsigned short)(rm>>16);
}

__device__ __forceinline__ unsigned short bf16rne(float x){
  unsigned int u = __float_as_uint(x);
  return (unsigned short)((u + 0x7FFF + ((u>>16)&1))>>16);
}
__device__ __forceinline__ float bf2f(unsigned short v){
  return __uint_as_float((unsigned int)v << 16);
}

// ---------- CSR build
__global__ void k_hist(const int* __restrict__ dst, int* __restrict__ cnt){
  int e = blockIdx.x*256 + threadIdx.x;
  if(e < EE) atomicAdd(&cnt[dst[e]], 1);
}

__global__ __launch_bounds__(1024) void k_scan(const int* __restrict__ cnt,
                                               int* __restrict__ rs, int* __restrict__ cur){
  __shared__ int part[1024];
  int t = threadIdx.x;
  const int CH = 10;
  int base = t*CH;
  int s = 0;
  #pragma unroll
  for(int j=0;j<CH;j++){ int i = base+j; if(i<NN) s += cnt[i]; }
  part[t] = s;
  __syncthreads();
  for(int off=1; off<1024; off<<=1){
    int v = (t>=off) ? part[t-off] : 0;
    __syncthreads();
    part[t] += v;
    __syncthreads();
  }
  int run = (t==0) ? 0 : part[t-1];
  #pragma unroll
  for(int j=0;j<CH;j++){
    int i = base+j;
    if(i<NN){ rs[i] = run; cur[i] = run; run += cnt[i]; }
  }
  if(t == 1023) rs[NN] = part[1023];
}

__global__ void k_fill(const int* __restrict__ dst,
                       int* __restrict__ cur, int* __restrict__ eid){
  int e = blockIdx.x*256 + threadIdx.x;
  if(e >= EE) return;
  int p = atomicAdd(&cur[dst[e]], 1);
  eid[p] = e;
}

// ---------- wave-parallel bitonic sort
__global__ __launch_bounds__(256) void k_sortcsr(const int* __restrict__ rs, int* __restrict__ eid,
                          const int* __restrict__ src, int* __restrict__ esrc){
  int wid  = (blockIdx.x*256 + threadIdx.x) >> 6;
  int lane = threadIdx.x & 63;
  if(wid >= NN) return;
  int jb = rs[wid], je = rs[wid+1];
  int deg = je - jb;
  if(deg <= 0) return;
  if(deg == 1){
    if(lane == 0) esrc[jb] = src[eid[jb]];
    return;
  }
  if(deg <= 64){
    int v = (lane < deg) ? eid[jb + lane] : 0x7FFFFFFF;
    #pragma unroll
    for(int k=2; k<=64; k<<=1){
      #pragma unroll
      for(int j=k>>1; j>0; j>>=1){
        int o = __shfl_xor(v, j, 64);
        bool desc  = (lane & k) != 0;
        bool lower = (lane & j) == 0;
        v = ((lower != desc) ? min(v,o) : max(v,o));
      }
    }
    if(lane < deg){
      eid[jb+lane]  = v;
      esrc[jb+lane] = src[v];
    }
  } else if(lane == 0){
    for(int j=jb+1; j<je; j++){
      int v = eid[j];
      int k = j-1;
      while(k >= jb && eid[k] > v){ eid[k+1] = eid[k]; k--; }
      eid[k+1] = v;
    }
    for(int j=jb; j<je; j++) esrc[j] = src[eid[j]];
  }
}

__global__ void k_gbounds(const int* __restrict__ batch, int* __restrict__ gs){
  int g = threadIdx.x;
  if(g > NG) return;
  if(g == NG){ gs[NG] = NN; return; }
  int lo = 0, hi = NN;
  while(lo < hi){
    int mid = (lo+hi)>>1;
    if(batch[mid] < g) lo = mid+1; else hi = mid;
  }
  gs[g] = lo;
}

// ---------- edge mask in CSR-permuted order
__global__ void k_emaskp(const int* __restrict__ src, const int* __restrict__ dst,
                         const int* __restrict__ eid, const float* __restrict__ nm,
                         float4* __restrict__ em4p){
  int j = blockIdx.x*256 + threadIdx.x;
  if(j >= EE) return;
  int e = eid[j];
  int s = src[e], d = dst[e];
  float4 m;
  m.x = nm[0*NN+s]*nm[0*NN+d];
  m.y = nm[1*NN+s]*nm[1*NN+d];
  m.z = nm[2*NN+s]*nm[2*NN+d];
  m.w = nm[3*NN+s]*nm[3*NN+d];
  em4p[j] = m;
}

// ---------- split W (fp32 -> 2x bf16) into MFMA B-fragment-linear layout
__global__ void k_splitW(const float* __restrict__ W, unsigned short* __restrict__ oh,
                         unsigned short* __restrict__ om, int nmat, int N){
  int tid = blockIdx.x*256 + threadIdx.x;
  int total = nmat*128*N;
  if(tid >= total) return;
  int mat = tid / (128*N);
  int rem = tid - mat*(128*N);
  int k = rem / N;
  int n = rem - k*N;
  int NF = N >> 4;
  int ks = k >> 5, kk = k & 31;
  int nf = n >> 4;
  int lane = (n & 15) + 16*((kk & 15) >> 2);
  int e = 4*(kk >> 4) + (kk & 3);
  size_t idx = (size_t)mat*128*N + ((size_t)(ks*NF + nf)*64 + lane)*8 + e;
  unsigned short hh, mm;
  split2(W[tid], hh, mm);
  oh[idx] = hh; om[idx] = mm;
}

// ---------- split edge_attr into CSR-permuted row-major SINGLE bf16 plane
__global__ void k_splitA(const float* __restrict__ A, const int* __restrict__ eid,
                         unsigned short* __restrict__ oh){
  int tid = blockIdx.x*256 + threadIdx.x;
  if(tid >= EE*32) return;
  int j = tid >> 5, kq = tid & 31;
  int k = kq*4;
  int rsrc = eid[j];
  float4 v = *(const float4*)&A[(size_t)rsrc*H + k];
  ushort4 hh;
  hh.x = bf16rne(v.x); hh.y = bf16rne(v.y);
  hh.z = bf16rne(v.z); hh.w = bf16rne(v.w);
  *(ushort4*)&oh[(size_t)j*H + k] = hh;
}

// ---------- unified split-input MFMA GEMM, no LDS, no barriers
// A planes ROW-MAJOR [row][128] (1 or 2 planes per A2); W planes frag-linear.
// OMODE: 0 = fp32 Cf, 1 = bf16x2 planes Oh/Om, 2 = single bf16 plane Oh.
template<int NFO, bool A2, bool GELU, int OMODE>
__global__ __launch_bounds__(256) void k_sgemm(
    const unsigned short* __restrict__ Ah, const unsigned short* __restrict__ Am,
    const unsigned short* __restrict__ Wh, const unsigned short* __restrict__ Wm,
    const float* __restrict__ bias, float* __restrict__ Cf,
    unsigned short* __restrict__ Oh, unsigned short* __restrict__ Om, int nrows){
  int t = threadIdx.x;
  int w = t >> 6, lane = t & 63;
  int m15 = lane & 15, kg = lane >> 4;
  int rowbase = blockIdx.x*128;

  const int SMAX = 4*NFO - 1;
  auto ldW = [&](int s, short8* d){
    size_t widx = ((size_t)s*64 + lane)*8;
    d[0] = *(const short8*)&Wh[widx];
    d[1] = *(const short8*)&Wm[widx];
  };

  int arow[2];
  #pragma unroll
  for(int mf=0;mf<2;mf++){
    int r = rowbase + w*32 + mf*16 + m15;
    arow[mf] = (r < nrows) ? r : (nrows-1);
  }

  f32x4 acc[2][NFO];
  #pragma unroll
  for(int mf=0;mf<2;mf++)
    #pragma unroll
    for(int nf=0;nf<NFO;nf++) acc[mf][nf] = (f32x4){0.f,0.f,0.f,0.f};

  short8 cw[2], nw[2];
  ldW(0, cw);
  ldW(1 <= SMAX ? 1 : SMAX, nw);

  for(int ks=0;ks<4;ks++){
    short8 ah[2], am[2];
    #pragma unroll
    for(int mf=0;mf<2;mf++){
      size_t base = (size_t)arow[mf]*H + ks*32 + kg*4;
      ushort4 hlo = *(const ushort4*)&Ah[base];
      ushort4 hhi = *(const ushort4*)&Ah[base + 16];
      ah[mf] = (short8){(short)hlo.x,(short)hlo.y,(short)hlo.z,(short)hlo.w,
                        (short)hhi.x,(short)hhi.y,(short)hhi.z,(short)hhi.w};
      if(A2){
        ushort4 mlo = *(const ushort4*)&Am[base];
        ushort4 mhi = *(const ushort4*)&Am[base + 16];
        am[mf] = (short8){(short)mlo.x,(short)mlo.y,(short)mlo.z,(short)mlo.w,
                          (short)mhi.x,(short)mhi.y,(short)mhi.z,(short)mhi.w};
      }
    }
    #pragma unroll
    for(int nf=0;nf<NFO;nf++){
      int s = ks*NFO + nf;
      short8 pw[2];
      ldW(s+2 <= SMAX ? s+2 : SMAX, pw);
      #pragma unroll
      for(int mf=0;mf<2;mf++){
        acc[mf][nf] = __builtin_amdgcn_mfma_f32_16x16x32_bf16(ah[mf], cw[0], acc[mf][nf], 0,0,0);
        acc[mf][nf] = __builtin_amdgcn_mfma_f32_16x16x32_bf16(ah[mf], cw[1], acc[mf][nf], 0,0,0);
        if(A2)
          acc[mf][nf] = __builtin_amdgcn_mfma_f32_16x16x32_bf16(am[mf], cw[0], acc[mf][nf], 0,0,0);
      }
      cw[0]=nw[0]; cw[1]=nw[1];
      nw[0]=pw[0]; nw[1]=pw[1];
    }
  }
  // epilogue: C/D layout col=lane&15, row=kg*4+r
  #pragma unroll
  for(int mf=0;mf<2;mf++){
    #pragma unroll
    for(int nf=0;nf<NFO;nf++){
      int gcol = nf*16 + m15;
      float bv = bias[gcol];
      #pragma unroll
      for(int r=0;r<4;r++){
        int grow = rowbase + w*32 + mf*16 + kg*4 + r;
        if(grow >= nrows) continue;
        float v = acc[mf][nf][r] + bv;
        if(GELU) v = gelu_f(v);
        size_t idx = (size_t)grow*(NFO*16) + gcol;
        if(OMODE == 0) Cf[idx] = v;
        if(OMODE == 1){
          unsigned short hh, mm2;
          split2(v, hh, mm2);
          Oh[idx] = hh; Om[idx] = mm2;
        }
        if(OMODE == 2) Oh[idx] = bf16rne(v);
      }
    }
  }
}

// ---------- aggregation: CSR streams; bf16 emb; node-major h gather (2KB/edge contiguous)
template<bool FIRST>
__global__ __launch_bounds__(256) void k_agg(const float* __restrict__ hin,
                       const unsigned short* __restrict__ embB, const float4* __restrict__ em4p,
                       const int* __restrict__ rs, const int* __restrict__ esrc,
                       const float* __restrict__ epsp,
                       unsigned short* __restrict__ Th, unsigned short* __restrict__ Tm){
  int t = threadIdx.x;
  int w = t >> 6;
  int lane = t & 63;
  int half = lane >> 5;
  int l32 = lane & 31;
  int n = blockIdx.x*4 + w;
  int d0 = l32*4;
  int rc0 = half*2, rc1 = rc0+1;
  float4 acc0 = {0.f,0.f,0.f,0.f}, acc1 = {0.f,0.f,0.f,0.f};
  int jb = rs[n], je = rs[n+1];

  float4 evs[3], h0s[3], h1s[3];
  float  m0s[3], m1s[3];

  auto ld = [&](int j, int slot){
    int s = esrc[j];
    ushort4 e4 = *(const ushort4*)&embB[(size_t)j*H + d0];
    evs[slot].x = bf2f(e4.x); evs[slot].y = bf2f(e4.y);
    evs[slot].z = bf2f(e4.z); evs[slot].w = bf2f(e4.w);
    float4 m = em4p[j];
    m0s[slot] = half ? m.z : m.x;
    m1s[slot] = half ? m.w : m.y;
    if(FIRST){
      h0s[slot] = *(const float4*)&hin[(size_t)s*H + d0];
      h1s[slot] = h0s[slot];
    } else {
      h0s[slot] = *(const float4*)&hin[((size_t)s*RCN + rc0)*H + d0];
      h1s[slot] = *(const float4*)&hin[((size_t)s*RCN + rc1)*H + d0];
    }
  };

  if(jb < je){
    ld(jb, 0);
    if(jb+1 < je) ld(jb+1, 1);
    if(jb+2 < je) ld(jb+2, 2);
    for(int j=jb; j<je; j++){
      float4 ev0 = evs[0], h00 = h0s[0], h10 = h1s[0];
      float  m00 = m0s[0], m10 = m1s[0];
      evs[0]=evs[1]; h0s[0]=h0s[1]; h1s[0]=h1s[1]; m0s[0]=m0s[1]; m1s[0]=m1s[1];
      evs[1]=evs[2]; h0s[1]=h0s[2]; h1s[1]=h1s[2]; m0s[1]=m0s[2]; m1s[1]=m1s[2];
      if(j+3 < je) ld(j+3, 2);
      if(FIRST){
        float gx = gelu_f(h00.x+ev0.x);
        float gy = gelu_f(h00.y+ev0.y);
        float gz = gelu_f(h00.z+ev0.z);
        float gw = gelu_f(h00.w+ev0.w);
        acc0.x += gx*m00; acc0.y += gy*m00; acc0.z += gz*m00; acc0.w += gw*m00;
        acc1.x += gx*m10; acc1.y += gy*m10; acc1.z += gz*m10; acc1.w += gw*m10;
      } else {
        acc0.x += gelu_f(h00.x+ev0.x)*m00;
        acc0.y += gelu_f(h00.y+ev0.y)*m00;
        acc0.z += gelu_f(h00.z+ev0.z)*m00;
        acc0.w += gelu_f(h00.w+ev0.w)*m00;
        acc1.x += gelu_f(h10.x+ev0.x)*m10;
        acc1.y += gelu_f(h10.y+ev0.y)*m10;
        acc1.z += gelu_f(h10.z+ev0.z)*m10;
        acc1.w += gelu_f(h10.w+ev0.w)*m10;
      }
    }
  }
  float e1 = 1.0f + epsp[0];
  #pragma unroll
  for(int p=0;p<2;p++){
    int rc = p ? rc1 : rc0;
    float4 ac = p ? acc1 : acc0;
    const float* hb = FIRST ? (hin + (size_t)n*H) : (hin + ((size_t)n*RCN + rc)*H);
    float4 hv = *(const float4*)&hb[d0];
    float4 o;
    o.x = e1*hv.x + ac.x; o.y = e1*hv.y + ac.y;
    o.z = e1*hv.z + ac.z; o.w = e1*hv.w + ac.w;
    int row = n*RCN + rc;               // node-major
    ushort4 hh, mm;
    split2(o.x, hh.x, mm.x);
    split2(o.y, hh.y, mm.y);
    split2(o.z, hh.z, mm.z);
    split2(o.w, hh.w, mm.w);
    size_t idx = (size_t)row*H + d0;
    *(ushort4*)&Th[idx] = hh;
    *(ushort4*)&Tm[idx] = mm;
  }
}

// ---------- deterministic masked segment mean (node-major y rows)
__global__ __launch_bounds__(64) void k_pool(const float* __restrict__ y, const float* __restrict__ nm,
                       const int* __restrict__ gs, float* __restrict__ out){
  int seg = blockIdx.x;
  int rc = seg / NG;
  int g  = seg - rc*NG;
  int c  = threadIdx.x;
  int nb = gs[g], ne = gs[g+1];
  float num = 0.f, den = 0.f;
  for(int n=nb; n<ne; n++){
    float w = nm[rc*NN + n];
    num += y[((size_t)n*RCN + rc)*OUTF + c] * w;
    den += w;
  }
  out[seg*OUTF + c] = num / fmaxf(den, 1e-12f);
}

extern "C" void kernel_launch(void* const* d_in, const int* in_sizes, int n_in,
                              void* d_out, int out_size, void* d_ws, size_t ws_size,
                              hipStream_t stream){
  const float* x         = (const float*)d_in[0];
  const float* edge_attr = (const float*)d_in[1];
  const float* node_mask = (const float*)d_in[2];
  const float* bond_W    = (const float*)d_in[3];
  const float* bond_b    = (const float*)d_in[4];
  const float* epsv      = (const float*)d_in[5];
  const float* conv_W1   = (const float*)d_in[6];
  const float* conv_b1   = (const float*)d_in[7];
  const float* conv_W2   = (const float*)d_in[8];
  const float* conv_b2   = (const float*)d_in[9];
  const float* mlp_W1    = (const float*)d_in[10];
  const float* mlp_b1    = (const float*)d_in[11];
  const float* mlp_W2    = (const float*)d_in[12];
  const float* mlp_b2    = (const float*)d_in[13];
  const int*   eidx      = (const int*)d_in[14];
  const int*   batch     = (const int*)d_in[15];
  const int* srcp = eidx;
  const int* dstp = eidx + EE;

  char* p = (char*)d_ws;
  auto alloc = [&](size_t bytes)->char*{
    char* r = p; p += (bytes + 255) & ~size_t(255); return r;
  };
  float*  h    = (float*) alloc((size_t)RCN*NN*H*4);      // 20.5 MB, node-major [n][rc][H]
  unsigned short* embB = (unsigned short*)alloc((size_t)EE*H*2);  // 41 MB bf16
  float4* em4p = (float4*)alloc((size_t)EE*16);           //  2.6 MB
  float*  y    = (float*) alloc((size_t)RCN*NN*OUTF*4);   // 10.2 MB
  int*    cnt  = (int*)   alloc((size_t)NN*4);
  int*    rs   = (int*)   alloc((size_t)(NN+1)*4);
  int*    cur  = (int*)   alloc((size_t)NN*4);
  int*    eid  = (int*)   alloc((size_t)EE*4);
  int*    esrc = (int*)   alloc((size_t)EE*4);
  int*    gs   = (int*)   alloc((size_t)(NG+1)*4);
  // weight planes (bf16x2, frag-linear)
  unsigned short* WBh  = (unsigned short*)alloc((size_t)3*16384*2);
  unsigned short* WBm  = (unsigned short*)alloc((size_t)3*16384*2);
  unsigned short* WC1h = (unsigned short*)alloc((size_t)3*16384*2);
  unsigned short* WC1m = (unsigned short*)alloc((size_t)3*16384*2);
  unsigned short* WC2h = (unsigned short*)alloc((size_t)3*16384*2);
  unsigned short* WC2m = (unsigned short*)alloc((size_t)3*16384*2);
  unsigned short* WM1h = (unsigned short*)alloc((size_t)16384*2);
  unsigned short* WM1m = (unsigned short*)alloc((size_t)16384*2);
  unsigned short* WM2h = (unsigned short*)alloc((size_t)8192*2);
  unsigned short* WM2m = (unsigned short*)alloc((size_t)8192*2);
  // edge_attr single bf16 plane (CSR-permuted, row-major): 41 MB
  unsigned short* EAh  = (unsigned short*)alloc((size_t)EE*H*2);
  // node activation planes (row-major bf16x2): 41 MB each pair
  const size_t NPB = (size_t)RCN*NN*H*2;
  unsigned short* TBh = (unsigned short*)alloc(NPB);
  unsigned short* TBm = (unsigned short*)alloc(NPB);
  unsigned short* Uh  = (unsigned short*)alloc(NPB);
  unsigned short* Um  = (unsigned short*)alloc(NPB);
  if((size_t)(p - (char*)d_ws) > ws_size) return;   // total ~199 MB

  hipMemsetAsync(cnt, 0, (size_t)NN*4, stream);

  k_hist    <<<(EE+255)/256, 256, 0, stream>>>(dstp, cnt);
  k_scan    <<<1, 1024, 0, stream>>>(cnt, rs, cur);
  k_fill    <<<(EE+255)/256, 256, 0, stream>>>(dstp, cur, eid);
  k_sortcsr <<<(NN*64+255)/256, 256, 0, stream>>>(rs, eid, srcp, esrc);
  k_emaskp  <<<(EE+255)/256, 256, 0, stream>>>(srcp, dstp, eid, node_mask, em4p);
  k_splitA  <<<EE*32/256, 256, 0, stream>>>(edge_attr, eid, EAh);
  k_gbounds <<<1, 128, 0, stream>>>(batch, gs);
  k_splitW  <<<192, 256, 0, stream>>>(bond_W,  WBh,  WBm,  3, 128);
  k_splitW  <<<192, 256, 0, stream>>>(conv_W1, WC1h, WC1m, 3, 128);
  k_splitW  <<<192, 256, 0, stream>>>(conv_W2, WC2h, WC2m, 3, 128);
  k_splitW  <<<64,  256, 0, stream>>>(mlp_W1,  WM1h, WM1m, 1, 128);
  k_splitW  <<<32,  256, 0, stream>>>(mlp_W2,  WM2h, WM2m, 1, 64);

  const int NROWS = RCN*NN;
  const int GB_E = EE/128;             // 1250
  const int GB_N = (NROWS+127)/128;    // 313
  for(int l=0; l<3; l++){
    size_t wo = (size_t)l*16384;
    // embB = bf16( edge_attr(CSR-perm) @ bond_W + b )   (A single-plane, 2-term)
    k_sgemm<8,false,false,2><<<GB_E, 256, 0, stream>>>(
        EAh, nullptr, WBh+wo, WBm+wo, bond_b + l*H, nullptr, embB, nullptr, EE);
    if(l == 0)
      k_agg<true ><<<NN/4, 256, 0, stream>>>(x, embB, em4p, rs, esrc, epsv + l, TBh, TBm);
    else
      k_agg<false><<<NN/4, 256, 0, stream>>>(h, embB, em4p, rs, esrc, epsv + l, TBh, TBm);
    // u = gelu(t @ W1 + b1) -> planes
    k_sgemm<8,true,true,1><<<GB_N, 256, 0, stream>>>(
        TBh, TBm, WC1h+wo, WC1m+wo, conv_b1 + l*H, nullptr, Uh, Um, NROWS);
    // h = gelu(u @ W2 + b2) -> fp32 (layers 0,1) or planes into TB (layer 2)
    if(l < 2)
      k_sgemm<8,true,true,0><<<GB_N, 256, 0, stream>>>(
          Uh, Um, WC2h+wo, WC2m+wo, conv_b2 + l*H, h, nullptr, nullptr, NROWS);
    else
      k_sgemm<8,true,true,1><<<GB_N, 256, 0, stream>>>(
          Uh, Um, WC2h+wo, WC2m+wo, conv_b2 + l*H, nullptr, TBh, TBm, NROWS);
  }
  // u2 = gelu(h_planes @ mlp_W1 + b1) -> planes (into U)
  k_sgemm<8,true,true,1><<<GB_N, 256, 0, stream>>>(
      TBh, TBm, WM1h, WM1m, mlp_b1, nullptr, Uh, Um, NROWS);
  // y = u2 @ mlp_W2 + b2 -> fp32
  k_sgemm<4,true,false,0><<<GB_N, 256, 0, stream>>>(
      Uh, Um, WM2h, WM2m, mlp_b2, y, nullptr, nullptr, NROWS);
  k_pool<<<DSEG, 64, 0, stream>>>(y, node_mask, gs, (float*)d_out);
}

// Round 14
// 559.018 us; speedup vs baseline: 1.4182x; 1.0972x over previous
//
#include <hip/hip_runtime.h>

constexpr int H    = 128;
constexpr int NN   = 10000;
constexpr int EE   = 160000;
constexpr int RCN  = 4;      // R*C
constexpr int NG   = 64;     // graphs per replica
constexpr int OUTF = 64;
constexpr int DSEG = 256;    // RCN*NG

using short8 = __attribute__((ext_vector_type(8))) short;
using f32x4  = __attribute__((ext_vector_type(4))) float;

// Exact-GELU via A&S 7.1.26 erf (|err|<=1.5e-7 abs)
__device__ __forceinline__ float gelu_f(float x){
  float z  = x*0.70710678118654752440f;
  float az = fabsf(z);
  float t  = __builtin_amdgcn_rcpf(fmaf(az, 0.3275911f, 1.0f));
  float e  = __expf(-z*z);
  float poly = fmaf(fmaf(fmaf(fmaf(1.061405429f, t, -1.453152027f),
                              t, 1.421413741f),
                         t, -0.284496736f),
                    t, 0.254829592f) * t;
  float er = fmaf(-poly, e, 1.0f);
  er = copysignf(er, z);
  return 0.5f*x*(1.0f + er);
}

// RNE 2-way split
__device__ __forceinline__ void split2(float x, unsigned short& h, unsigned short& m){
  unsigned int u = __float_as_uint(x);
  unsigned int rh = u + 0x7FFF + ((u>>16)&1);
  h = (unsigned short)(rh>>16);
  float fh = __uint_as_float((unsigned int)h << 16);
  float r1 = x - fh;
  unsigned int u1 = __float_as_uint(r1);
  unsigned int rm = u1 + 0x7FFF + ((u1>>16)&1);
  m = (unsigned short)(rm>>16);
}

__device__ __forceinline__ unsigned short bf16rne(float x){
  unsigned int u = __float_as_uint(x);
  return (unsigned short)((u + 0x7FFF + ((u>>16)&1))>>16);
}
__device__ __forceinline__ float bf2f(unsigned short v){
  return __uint_as_float((unsigned int)v << 16);
}

// ---------- CSR build
__global__ void k_hist(const int* __restrict__ dst, int* __restrict__ cnt){
  int e = blockIdx.x*256 + threadIdx.x;
  if(e < EE) atomicAdd(&cnt[dst[e]], 1);
}

__global__ __launch_bounds__(1024) void k_scan(const int* __restrict__ cnt,
                                               int* __restrict__ rs, int* __restrict__ cur){
  __shared__ int part[1024];
  int t = threadIdx.x;
  const int CH = 10;
  int base = t*CH;
  int s = 0;
  #pragma unroll
  for(int j=0;j<CH;j++){ int i = base+j; if(i<NN) s += cnt[i]; }
  part[t] = s;
  __syncthreads();
  for(int off=1; off<1024; off<<=1){
    int v = (t>=off) ? part[t-off] : 0;
    __syncthreads();
    part[t] += v;
    __syncthreads();
  }
  int run = (t==0) ? 0 : part[t-1];
  #pragma unroll
  for(int j=0;j<CH;j++){
    int i = base+j;
    if(i<NN){ rs[i] = run; cur[i] = run; run += cnt[i]; }
  }
  if(t == 1023) rs[NN] = part[1023];
}

__global__ void k_fill(const int* __restrict__ dst,
                       int* __restrict__ cur, int* __restrict__ eid){
  int e = blockIdx.x*256 + threadIdx.x;
  if(e >= EE) return;
  int p = atomicAdd(&cur[dst[e]], 1);
  eid[p] = e;
}

// ---------- wave-parallel bitonic sort
__global__ __launch_bounds__(256) void k_sortcsr(const int* __restrict__ rs, int* __restrict__ eid,
                          const int* __restrict__ src, int* __restrict__ esrc){
  int wid  = (blockIdx.x*256 + threadIdx.x) >> 6;
  int lane = threadIdx.x & 63;
  if(wid >= NN) return;
  int jb = rs[wid], je = rs[wid+1];
  int deg = je - jb;
  if(deg <= 0) return;
  if(deg == 1){
    if(lane == 0) esrc[jb] = src[eid[jb]];
    return;
  }
  if(deg <= 64){
    int v = (lane < deg) ? eid[jb + lane] : 0x7FFFFFFF;
    #pragma unroll
    for(int k=2; k<=64; k<<=1){
      #pragma unroll
      for(int j=k>>1; j>0; j>>=1){
        int o = __shfl_xor(v, j, 64);
        bool desc  = (lane & k) != 0;
        bool lower = (lane & j) == 0;
        v = ((lower != desc) ? min(v,o) : max(v,o));
      }
    }
    if(lane < deg){
      eid[jb+lane]  = v;
      esrc[jb+lane] = src[v];
    }
  } else if(lane == 0){
    for(int j=jb+1; j<je; j++){
      int v = eid[j];
      int k = j-1;
      while(k >= jb && eid[k] > v){ eid[k+1] = eid[k]; k--; }
      eid[k+1] = v;
    }
    for(int j=jb; j<je; j++) esrc[j] = src[eid[j]];
  }
}

__global__ void k_gbounds(const int* __restrict__ batch, int* __restrict__ gs){
  int g = threadIdx.x;
  if(g > NG) return;
  if(g == NG){ gs[NG] = NN; return; }
  int lo = 0, hi = NN;
  while(lo < hi){
    int mid = (lo+hi)>>1;
    if(batch[mid] < g) lo = mid+1; else hi = mid;
  }
  gs[g] = lo;
}

// ---------- edge mask in CSR-permuted order
__global__ void k_emaskp(const int* __restrict__ src, const int* __restrict__ dst,
                         const int* __restrict__ eid, const float* __restrict__ nm,
                         float4* __restrict__ em4p){
  int j = blockIdx.x*256 + threadIdx.x;
  if(j >= EE) return;
  int e = eid[j];
  int s = src[e], d = dst[e];
  float4 m;
  m.x = nm[0*NN+s]*nm[0*NN+d];
  m.y = nm[1*NN+s]*nm[1*NN+d];
  m.z = nm[2*NN+s]*nm[2*NN+d];
  m.w = nm[3*NN+s]*nm[3*NN+d];
  em4p[j] = m;
}

// ---------- split W (fp32 -> 2x bf16) into MFMA B-fragment-linear layout
__global__ void k_splitW(const float* __restrict__ W, unsigned short* __restrict__ oh,
                         unsigned short* __restrict__ om, int nmat, int N){
  int tid = blockIdx.x*256 + threadIdx.x;
  int total = nmat*128*N;
  if(tid >= total) return;
  int mat = tid / (128*N);
  int rem = tid - mat*(128*N);
  int k = rem / N;
  int n = rem - k*N;
  int NF = N >> 4;
  int ks = k >> 5, kk = k & 31;
  int nf = n >> 4;
  int lane = (n & 15) + 16*((kk & 15) >> 2);
  int e = 4*(kk >> 4) + (kk & 3);
  size_t idx = (size_t)mat*128*N + ((size_t)(ks*NF + nf)*64 + lane)*8 + e;
  unsigned short hh, mm;
  split2(W[tid], hh, mm);
  oh[idx] = hh; om[idx] = mm;
}

// ---------- split edge_attr into CSR-permuted row-major SINGLE bf16 plane
__global__ void k_splitA(const float* __restrict__ A, const int* __restrict__ eid,
                         unsigned short* __restrict__ oh){
  int tid = blockIdx.x*256 + threadIdx.x;
  if(tid >= EE*32) return;
  int j = tid >> 5, kq = tid & 31;
  int k = kq*4;
  int rsrc = eid[j];
  float4 v = *(const float4*)&A[(size_t)rsrc*H + k];
  ushort4 hh;
  hh.x = bf16rne(v.x); hh.y = bf16rne(v.y);
  hh.z = bf16rne(v.z); hh.w = bf16rne(v.w);
  *(ushort4*)&oh[(size_t)j*H + k] = hh;
}

// ---------- single split-input MFMA GEMM (emb path), no LDS, no barriers
// A planes ROW-MAJOR [row][128] (A2 selects 1 or 2 planes); W planes frag-linear.
// OMODE: 0 = fp32 Cf, 1 = bf16x2 planes Oh/Om, 2 = single bf16 plane Oh.
template<int NFO, bool A2, bool GELU, int OMODE>
__global__ __launch_bounds__(256) void k_sgemm(
    const unsigned short* __restrict__ Ah, const unsigned short* __restrict__ Am,
    const unsigned short* __restrict__ Wh, const unsigned short* __restrict__ Wm,
    const float* __restrict__ bias, float* __restrict__ Cf,
    unsigned short* __restrict__ Oh, unsigned short* __restrict__ Om, int nrows){
  int t = threadIdx.x;
  int w = t >> 6, lane = t & 63;
  int m15 = lane & 15, kg = lane >> 4;
  int rowbase = blockIdx.x*128;

  const int SMAX = 4*NFO - 1;
  auto ldW = [&](int s, short8* d){
    size_t widx = ((size_t)s*64 + lane)*8;
    d[0] = *(const short8*)&Wh[widx];
    d[1] = *(const short8*)&Wm[widx];
  };

  int arow[2];
  #pragma unroll
  for(int mf=0;mf<2;mf++){
    int r = rowbase + w*32 + mf*16 + m15;
    arow[mf] = (r < nrows) ? r : (nrows-1);
  }

  f32x4 acc[2][NFO];
  #pragma unroll
  for(int mf=0;mf<2;mf++)
    #pragma unroll
    for(int nf=0;nf<NFO;nf++) acc[mf][nf] = (f32x4){0.f,0.f,0.f,0.f};

  short8 cw[2], nw[2];
  ldW(0, cw);
  ldW(1 <= SMAX ? 1 : SMAX, nw);

  for(int ks=0;ks<4;ks++){
    short8 ah[2], am[2];
    #pragma unroll
    for(int mf=0;mf<2;mf++){
      size_t base = (size_t)arow[mf]*H + ks*32 + kg*4;
      ushort4 hlo = *(const ushort4*)&Ah[base];
      ushort4 hhi = *(const ushort4*)&Ah[base + 16];
      ah[mf] = (short8){(short)hlo.x,(short)hlo.y,(short)hlo.z,(short)hlo.w,
                        (short)hhi.x,(short)hhi.y,(short)hhi.z,(short)hhi.w};
      if(A2){
        ushort4 mlo = *(const ushort4*)&Am[base];
        ushort4 mhi = *(const ushort4*)&Am[base + 16];
        am[mf] = (short8){(short)mlo.x,(short)mlo.y,(short)mlo.z,(short)mlo.w,
                          (short)mhi.x,(short)mhi.y,(short)mhi.z,(short)mhi.w};
      }
    }
    #pragma unroll
    for(int nf=0;nf<NFO;nf++){
      int s = ks*NFO + nf;
      short8 pw[2];
      ldW(s+2 <= SMAX ? s+2 : SMAX, pw);
      #pragma unroll
      for(int mf=0;mf<2;mf++){
        acc[mf][nf] = __builtin_amdgcn_mfma_f32_16x16x32_bf16(ah[mf], cw[0], acc[mf][nf], 0,0,0);
        acc[mf][nf] = __builtin_amdgcn_mfma_f32_16x16x32_bf16(ah[mf], cw[1], acc[mf][nf], 0,0,0);
        if(A2)
          acc[mf][nf] = __builtin_amdgcn_mfma_f32_16x16x32_bf16(am[mf], cw[0], acc[mf][nf], 0,0,0);
      }
      cw[0]=nw[0]; cw[1]=nw[1];
      nw[0]=pw[0]; nw[1]=pw[1];
    }
  }
  #pragma unroll
  for(int mf=0;mf<2;mf++){
    #pragma unroll
    for(int nf=0;nf<NFO;nf++){
      int gcol = nf*16 + m15;
      float bv = bias[gcol];
      #pragma unroll
      for(int r=0;r<4;r++){
        int grow = rowbase + w*32 + mf*16 + kg*4 + r;
        if(grow >= nrows) continue;
        float v = acc[mf][nf][r] + bv;
        if(GELU) v = gelu_f(v);
        size_t idx = (size_t)grow*(NFO*16) + gcol;
        if(OMODE == 0) Cf[idx] = v;
        if(OMODE == 1){
          unsigned short hh, mm2;
          split2(v, hh, mm2);
          Oh[idx] = hh; Om[idx] = mm2;
        }
        if(OMODE == 2) Oh[idx] = bf16rne(v);
      }
    }
  }
}

// ---------- FUSED double GEMM: out = act2( gelu(A@W1+b1) @ W2 + b2 )
// A planes (bf16x2, row-major); W planes frag-linear. Intermediate u lives in a
// per-wave LDS tile (packed h|m<<16), transposed C/D->A layout wave-internally.
// OMODE: 0 = fp32 Cf, 1 = bf16x2 planes Oh/Om.
template<int NFO2, bool G2, int OMODE>
__global__ __launch_bounds__(256) void k_fuse2(
    const unsigned short* __restrict__ Ah, const unsigned short* __restrict__ Am,
    const unsigned short* __restrict__ W1h, const unsigned short* __restrict__ W1m,
    const float* __restrict__ b1,
    const unsigned short* __restrict__ W2h, const unsigned short* __restrict__ W2m,
    const float* __restrict__ b2,
    float* __restrict__ Cf,
    unsigned short* __restrict__ Oh, unsigned short* __restrict__ Om, int nrows){
  __shared__ unsigned int Ul[4*32*132];   // 67.6 KB: per-wave 32x132 packed u32
  int t = threadIdx.x;
  int w = t >> 6, lane = t & 63;
  int m15 = lane & 15, kg = lane >> 4;
  int rowbase = blockIdx.x*128;
  unsigned int* Uw = &Ul[w*32*132];

  int arow[2];
  #pragma unroll
  for(int mf=0;mf<2;mf++){
    int r = rowbase + w*32 + mf*16 + m15;
    arow[mf] = (r < nrows) ? r : (nrows-1);
  }

  // ---- phase 1: u = gelu(A@W1 + b1), NFO1=8, A2=true
  {
    const int SMAX = 31;
    auto ldW = [&](int s, short8* d){
      size_t widx = ((size_t)s*64 + lane)*8;
      d[0] = *(const short8*)&W1h[widx];
      d[1] = *(const short8*)&W1m[widx];
    };
    f32x4 acc[2][8];
    #pragma unroll
    for(int mf=0;mf<2;mf++)
      #pragma unroll
      for(int nf=0;nf<8;nf++) acc[mf][nf] = (f32x4){0.f,0.f,0.f,0.f};
    short8 cw[2], nw[2];
    ldW(0, cw); ldW(1, nw);
    for(int ks=0;ks<4;ks++){
      short8 ah[2], am[2];
      #pragma unroll
      for(int mf=0;mf<2;mf++){
        size_t base = (size_t)arow[mf]*H + ks*32 + kg*4;
        ushort4 hlo = *(const ushort4*)&Ah[base];
        ushort4 hhi = *(const ushort4*)&Ah[base + 16];
        ushort4 mlo = *(const ushort4*)&Am[base];
        ushort4 mhi = *(const ushort4*)&Am[base + 16];
        ah[mf] = (short8){(short)hlo.x,(short)hlo.y,(short)hlo.z,(short)hlo.w,
                          (short)hhi.x,(short)hhi.y,(short)hhi.z,(short)hhi.w};
        am[mf] = (short8){(short)mlo.x,(short)mlo.y,(short)mlo.z,(short)mlo.w,
                          (short)mhi.x,(short)mhi.y,(short)mhi.z,(short)mhi.w};
      }
      #pragma unroll
      for(int nf=0;nf<8;nf++){
        int s = ks*8 + nf;
        short8 pw[2];
        ldW(s+2 <= SMAX ? s+2 : SMAX, pw);
        #pragma unroll
        for(int mf=0;mf<2;mf++){
          acc[mf][nf] = __builtin_amdgcn_mfma_f32_16x16x32_bf16(ah[mf], cw[0], acc[mf][nf], 0,0,0);
          acc[mf][nf] = __builtin_amdgcn_mfma_f32_16x16x32_bf16(ah[mf], cw[1], acc[mf][nf], 0,0,0);
          acc[mf][nf] = __builtin_amdgcn_mfma_f32_16x16x32_bf16(am[mf], cw[0], acc[mf][nf], 0,0,0);
        }
        cw[0]=nw[0]; cw[1]=nw[1];
        nw[0]=pw[0]; nw[1]=pw[1];
      }
    }
    // epilogue -> LDS (packed h|m), within-wave transpose target
    #pragma unroll
    for(int mf=0;mf<2;mf++){
      #pragma unroll
      for(int nf=0;nf<8;nf++){
        float bv = b1[nf*16 + m15];
        #pragma unroll
        for(int r=0;r<4;r++){
          float v = gelu_f(acc[mf][nf][r] + bv);
          unsigned short hh, mm2;
          split2(v, hh, mm2);
          int wrow = mf*16 + kg*4 + r;
          Uw[wrow*132 + nf*16 + m15] = (unsigned)hh | ((unsigned)mm2 << 16);
        }
      }
    }
  }
  __syncthreads();

  // ---- phase 2: out = act2(u @ W2 + b2)
  {
    const int SMAX = 4*NFO2 - 1;
    auto ldW = [&](int s, short8* d){
      size_t widx = ((size_t)s*64 + lane)*8;
      d[0] = *(const short8*)&W2h[widx];
      d[1] = *(const short8*)&W2m[widx];
    };
    f32x4 acc[2][NFO2];
    #pragma unroll
    for(int mf=0;mf<2;mf++)
      #pragma unroll
      for(int nf=0;nf<NFO2;nf++) acc[mf][nf] = (f32x4){0.f,0.f,0.f,0.f};
    short8 cw[2], nw[2];
    ldW(0, cw); ldW(1 <= SMAX ? 1 : SMAX, nw);
    for(int ks=0;ks<4;ks++){
      short8 ah[2], am[2];
      #pragma unroll
      for(int mf=0;mf<2;mf++){
        const unsigned int* base = &Uw[(mf*16 + m15)*132 + ks*32 + kg*4];
        uint4 q0 = *(const uint4*)base;
        uint4 q1 = *(const uint4*)(base + 16);
        unsigned h0 = (q0.x & 0xFFFFu) | (q0.y << 16);
        unsigned h1 = (q0.z & 0xFFFFu) | (q0.w << 16);
        unsigned h2 = (q1.x & 0xFFFFu) | (q1.y << 16);
        unsigned h3 = (q1.z & 0xFFFFu) | (q1.w << 16);
        unsigned M0 = (q0.x >> 16) | (q0.y & 0xFFFF0000u);
        unsigned M1 = (q0.z >> 16) | (q0.w & 0xFFFF0000u);
        unsigned M2 = (q1.x >> 16) | (q1.y & 0xFFFF0000u);
        unsigned M3 = (q1.z >> 16) | (q1.w & 0xFFFF0000u);
        union { uint4 u; short8 s; } cvh, cvm;
        cvh.u = (uint4){h0,h1,h2,h3};
        cvm.u = (uint4){M0,M1,M2,M3};
        ah[mf] = cvh.s; am[mf] = cvm.s;
      }
      #pragma unroll
      for(int nf=0;nf<NFO2;nf++){
        int s = ks*NFO2 + nf;
        short8 pw[2];
        ldW(s+2 <= SMAX ? s+2 : SMAX, pw);
        #pragma unroll
        for(int mf=0;mf<2;mf++){
          acc[mf][nf] = __builtin_amdgcn_mfma_f32_16x16x32_bf16(ah[mf], cw[0], acc[mf][nf], 0,0,0);
          acc[mf][nf] = __builtin_amdgcn_mfma_f32_16x16x32_bf16(ah[mf], cw[1], acc[mf][nf], 0,0,0);
          acc[mf][nf] = __builtin_amdgcn_mfma_f32_16x16x32_bf16(am[mf], cw[0], acc[mf][nf], 0,0,0);
        }
        cw[0]=nw[0]; cw[1]=nw[1];
        nw[0]=pw[0]; nw[1]=pw[1];
      }
    }
    #pragma unroll
    for(int mf=0;mf<2;mf++){
      #pragma unroll
      for(int nf=0;nf<NFO2;nf++){
        int gcol = nf*16 + m15;
        float bv = b2[gcol];
        #pragma unroll
        for(int r=0;r<4;r++){
          int grow = rowbase + w*32 + mf*16 + kg*4 + r;
          if(grow >= nrows) continue;
          float v = acc[mf][nf][r] + bv;
          if(G2) v = gelu_f(v);
          size_t idx = (size_t)grow*(NFO2*16) + gcol;
          if(OMODE == 0) Cf[idx] = v;
          if(OMODE == 1){
            unsigned short hh, mm2;
            split2(v, hh, mm2);
            Oh[idx] = hh; Om[idx] = mm2;
          }
        }
      }
    }
  }
}

// ---------- aggregation: CSR streams; bf16 emb; node-major h gather;
// 3-slot ROTATION pipeline (no register shifting)
#define AGG_LD(J, EV, H0, H1, M0, M1) do{                                   \
    int s_ = esrc[(J)];                                                     \
    ushort4 e4_ = *(const ushort4*)&embB[(size_t)(J)*H + d0];               \
    EV.x = bf2f(e4_.x); EV.y = bf2f(e4_.y);                                 \
    EV.z = bf2f(e4_.z); EV.w = bf2f(e4_.w);                                 \
    float4 m_ = em4p[(J)];                                                  \
    M0 = half ? m_.z : m_.x;                                                \
    M1 = half ? m_.w : m_.y;                                                \
    if(FIRST){                                                              \
      H0 = *(const float4*)&hin[(size_t)s_*H + d0];                         \
      H1 = H0;                                                              \
    } else {                                                                \
      H0 = *(const float4*)&hin[((size_t)s_*RCN + rc0)*H + d0];             \
      H1 = *(const float4*)&hin[((size_t)s_*RCN + rc1)*H + d0];             \
    }                                                                       \
  }while(0)

#define AGG_STEP(EV, H0, H1, M0, M1) do{                                    \
    if(FIRST){                                                              \
      float gx = gelu_f(H0.x+EV.x);                                         \
      float gy = gelu_f(H0.y+EV.y);                                         \
      float gz = gelu_f(H0.z+EV.z);                                         \
      float gw = gelu_f(H0.w+EV.w);                                         \
      acc0.x += gx*M0; acc0.y += gy*M0; acc0.z += gz*M0; acc0.w += gw*M0;   \
      acc1.x += gx*M1; acc1.y += gy*M1; acc1.z += gz*M1; acc1.w += gw*M1;   \
    } else {                                                                \
      acc0.x += gelu_f(H0.x+EV.x)*M0;                                       \
      acc0.y += gelu_f(H0.y+EV.y)*M0;                                       \
      acc0.z += gelu_f(H0.z+EV.z)*M0;                                       \
      acc0.w += gelu_f(H0.w+EV.w)*M0;                                       \
      acc1.x += gelu_f(H1.x+EV.x)*M1;                                       \
      acc1.y += gelu_f(H1.y+EV.y)*M1;                                       \
      acc1.z += gelu_f(H1.z+EV.z)*M1;                                       \
      acc1.w += gelu_f(H1.w+EV.w)*M1;                                       \
    }                                                                       \
  }while(0)

template<bool FIRST>
__global__ __launch_bounds__(256) void k_agg(const float* __restrict__ hin,
                       const unsigned short* __restrict__ embB, const float4* __restrict__ em4p,
                       const int* __restrict__ rs, const int* __restrict__ esrc,
                       const float* __restrict__ epsp,
                       unsigned short* __restrict__ Th, unsigned short* __restrict__ Tm){
  int t = threadIdx.x;
  int w = t >> 6;
  int lane = t & 63;
  int half = lane >> 5;
  int l32 = lane & 31;
  int n = blockIdx.x*4 + w;
  int d0 = l32*4;
  int rc0 = half*2, rc1 = rc0+1;
  float4 acc0 = {0.f,0.f,0.f,0.f}, acc1 = {0.f,0.f,0.f,0.f};
  int jb = rs[n], je = rs[n+1];

  float4 ev0, h00, h10, ev1, h01, h11, ev2, h02, h12;
  float  m00, m10, m01, m11, m02, m12;

  if(jb < je){
    AGG_LD(jb, ev0, h00, h10, m00, m10);
    if(jb+1 < je) AGG_LD(jb+1, ev1, h01, h11, m01, m11);
    if(jb+2 < je) AGG_LD(jb+2, ev2, h02, h12, m02, m12);
    int j = jb;
    for(;;){
      AGG_STEP(ev0, h00, h10, m00, m10);
      if(j+3 < je) AGG_LD(j+3, ev0, h00, h10, m00, m10);
      if(++j >= je) break;
      AGG_STEP(ev1, h01, h11, m01, m11);
      if(j+3 < je) AGG_LD(j+3, ev1, h01, h11, m01, m11);
      if(++j >= je) break;
      AGG_STEP(ev2, h02, h12, m02, m12);
      if(j+3 < je) AGG_LD(j+3, ev2, h02, h12, m02, m12);
      if(++j >= je) break;
    }
  }
  float e1 = 1.0f + epsp[0];
  #pragma unroll
  for(int p=0;p<2;p++){
    int rc = p ? rc1 : rc0;
    float4 ac = p ? acc1 : acc0;
    const float* hb = FIRST ? (hin + (size_t)n*H) : (hin + ((size_t)n*RCN + rc)*H);
    float4 hv = *(const float4*)&hb[d0];
    float4 o;
    o.x = e1*hv.x + ac.x; o.y = e1*hv.y + ac.y;
    o.z = e1*hv.z + ac.z; o.w = e1*hv.w + ac.w;
    int row = n*RCN + rc;               // node-major
    ushort4 hh, mm;
    split2(o.x, hh.x, mm.x);
    split2(o.y, hh.y, mm.y);
    split2(o.z, hh.z, mm.z);
    split2(o.w, hh.w, mm.w);
    size_t idx = (size_t)row*H + d0;
    *(ushort4*)&Th[idx] = hh;
    *(ushort4*)&Tm[idx] = mm;
  }
}

// ---------- deterministic masked segment mean (node-major y rows)
__global__ __launch_bounds__(64) void k_pool(const float* __restrict__ y, const float* __restrict__ nm,
                       const int* __restrict__ gs, float* __restrict__ out){
  int seg = blockIdx.x;
  int rc = seg / NG;
  int g  = seg - rc*NG;
  int c  = threadIdx.x;
  int nb = gs[g], ne = gs[g+1];
  float num = 0.f, den = 0.f;
  for(int n=nb; n<ne; n++){
    float w = nm[rc*NN + n];
    num += y[((size_t)n*RCN + rc)*OUTF + c] * w;
    den += w;
  }
  out[seg*OUTF + c] = num / fmaxf(den, 1e-12f);
}

extern "C" void kernel_launch(void* const* d_in, const int* in_sizes, int n_in,
                              void* d_out, int out_size, void* d_ws, size_t ws_size,
                              hipStream_t stream){
  const float* x         = (const float*)d_in[0];
  const float* edge_attr = (const float*)d_in[1];
  const float* node_mask = (const float*)d_in[2];
  const float* bond_W    = (const float*)d_in[3];
  const float* bond_b    = (const float*)d_in[4];
  const float* epsv      = (const float*)d_in[5];
  const float* conv_W1   = (const float*)d_in[6];
  const float* conv_b1   = (const float*)d_in[7];
  const float* conv_W2   = (const float*)d_in[8];
  const float* conv_b2   = (const float*)d_in[9];
  const float* mlp_W1    = (const float*)d_in[10];
  const float* mlp_b1    = (const float*)d_in[11];
  const float* mlp_W2    = (const float*)d_in[12];
  const float* mlp_b2    = (const float*)d_in[13];
  const int*   eidx      = (const int*)d_in[14];
  const int*   batch     = (const int*)d_in[15];
  const int* srcp = eidx;
  const int* dstp = eidx + EE;

  char* p = (char*)d_ws;
  auto alloc = [&](size_t bytes)->char*{
    char* r = p; p += (bytes + 255) & ~size_t(255); return r;
  };
  float*  h    = (float*) alloc((size_t)RCN*NN*H*4);      // 20.5 MB, node-major [n][rc][H]
  unsigned short* embB = (unsigned short*)alloc((size_t)EE*H*2);  // 41 MB bf16
  float4* em4p = (float4*)alloc((size_t)EE*16);           //  2.6 MB
  float*  y    = (float*) alloc((size_t)RCN*NN*OUTF*4);   // 10.2 MB
  int*    cnt  = (int*)   alloc((size_t)NN*4);
  int*    rs   = (int*)   alloc((size_t)(NN+1)*4);
  int*    cur  = (int*)   alloc((size_t)NN*4);
  int*    eid  = (int*)   alloc((size_t)EE*4);
  int*    esrc = (int*)   alloc((size_t)EE*4);
  int*    gs   = (int*)   alloc((size_t)(NG+1)*4);
  // weight planes (bf16x2, frag-linear)
  unsigned short* WBh  = (unsigned short*)alloc((size_t)3*16384*2);
  unsigned short* WBm  = (unsigned short*)alloc((size_t)3*16384*2);
  unsigned short* WC1h = (unsigned short*)alloc((size_t)3*16384*2);
  unsigned short* WC1m = (unsigned short*)alloc((size_t)3*16384*2);
  unsigned short* WC2h = (unsigned short*)alloc((size_t)3*16384*2);
  unsigned short* WC2m = (unsigned short*)alloc((size_t)3*16384*2);
  unsigned short* WM1h = (unsigned short*)alloc((size_t)16384*2);
  unsigned short* WM1m = (unsigned short*)alloc((size_t)16384*2);
  unsigned short* WM2h = (unsigned short*)alloc((size_t)8192*2);
  unsigned short* WM2m = (unsigned short*)alloc((size_t)8192*2);
  // edge_attr single bf16 plane (CSR-permuted, row-major): 41 MB
  unsigned short* EAh  = (unsigned short*)alloc((size_t)EE*H*2);
  // node activation planes (row-major bf16x2): 41 MB
  const size_t NPB = (size_t)RCN*NN*H*2;
  unsigned short* TBh = (unsigned short*)alloc(NPB);
  unsigned short* TBm = (unsigned short*)alloc(NPB);
  if((size_t)(p - (char*)d_ws) > ws_size) return;   // total ~158 MB

  hipMemsetAsync(cnt, 0, (size_t)NN*4, stream);

  k_hist    <<<(EE+255)/256, 256, 0, stream>>>(dstp, cnt);
  k_scan    <<<1, 1024, 0, stream>>>(cnt, rs, cur);
  k_fill    <<<(EE+255)/256, 256, 0, stream>>>(dstp, cur, eid);
  k_sortcsr <<<(NN*64+255)/256, 256, 0, stream>>>(rs, eid, srcp, esrc);
  k_emaskp  <<<(EE+255)/256, 256, 0, stream>>>(srcp, dstp, eid, node_mask, em4p);
  k_splitA  <<<EE*32/256, 256, 0, stream>>>(edge_attr, eid, EAh);
  k_gbounds <<<1, 128, 0, stream>>>(batch, gs);
  k_splitW  <<<192, 256, 0, stream>>>(bond_W,  WBh,  WBm,  3, 128);
  k_splitW  <<<192, 256, 0, stream>>>(conv_W1, WC1h, WC1m, 3, 128);
  k_splitW  <<<192, 256, 0, stream>>>(conv_W2, WC2h, WC2m, 3, 128);
  k_splitW  <<<64,  256, 0, stream>>>(mlp_W1,  WM1h, WM1m, 1, 128);
  k_splitW  <<<32,  256, 0, stream>>>(mlp_W2,  WM2h, WM2m, 1, 64);

  const int NROWS = RCN*NN;
  const int GB_E = EE/128;             // 1250
  const int GB_N = (NROWS+127)/128;    // 313
  for(int l=0; l<3; l++){
    size_t wo = (size_t)l*16384;
    // embB = bf16( edge_attr(CSR-perm) @ bond_W + b )
    k_sgemm<8,false,false,2><<<GB_E, 256, 0, stream>>>(
        EAh, nullptr, WBh+wo, WBm+wo, bond_b + l*H, nullptr, embB, nullptr, EE);
    if(l == 0)
      k_agg<true ><<<NN/4, 256, 0, stream>>>(x, embB, em4p, rs, esrc, epsv + l, TBh, TBm);
    else
      k_agg<false><<<NN/4, 256, 0, stream>>>(h, embB, em4p, rs, esrc, epsv + l, TBh, TBm);
    // fused conv: h = gelu(gelu(t@W1+b1)@W2+b2); fp32 out for layers 0,1; planes for layer 2
    if(l < 2)
      k_fuse2<8,true,0><<<GB_N, 256, 0, stream>>>(
          TBh, TBm, WC1h+wo, WC1m+wo, conv_b1 + l*H,
          WC2h+wo, WC2m+wo, conv_b2 + l*H, h, nullptr, nullptr, NROWS);
    else
      k_fuse2<8,true,1><<<GB_N, 256, 0, stream>>>(
          TBh, TBm, WC1h+wo, WC1m+wo, conv_b1 + l*H,
          WC2h+wo, WC2m+wo, conv_b2 + l*H, nullptr, TBh, TBm, NROWS);
  }
  // fused MLP: y = gelu(hp@W1+b1)@W2+b2
  k_fuse2<4,false,0><<<GB_N, 256, 0, stream>>>(
      TBh, TBm, WM1h, WM1m, mlp_b1, WM2h, WM2m, mlp_b2,
      y, nullptr, nullptr, NROWS);
  k_pool<<<DSEG, 64, 0, stream>>>(y, node_mask, gs, (float*)d_out);
}